// Round 2
// baseline (2859.975 us; speedup 1.0000x reference)
//
#include <hip/hip_runtime.h>

// ScannedRNN (flax GRUCell with per-step carry reset), T=512, B=128, H=512.
// R4: coalesced wave-per-row chain matvec. R3's k_chain read WhT with each
// lane 1KB apart (64 cache lines per load instr -> ~1ms). Now one wave
// computes one output row: lane l loads WhT[n][l*8..+8] (contiguous 1KB per
// wave instr), 8 FMAs vs h-fragment in registers, 6-round shfl_xor reduce.
// Everything else unchanged from R3:
//   sealed-chunk cut: k_bound parallel-fills hin; k_chain only propagates
//   the ~32 transparent runs; phase3 produces `out` for fr==8 rows.

typedef _Float16 f16;
typedef _Float16 f16x8 __attribute__((ext_vector_type(8)));
typedef float f32x4 __attribute__((ext_vector_type(4)));

#define TT 512
#define BB 128
#define HH 512
#define H3 1536
#define TBR 65536                     // TT*BB rows
#define NC 64                         // chunks
#define CL 8                          // chunk length
#define NR 8192                       // NC*BB rows of chunk-state
static const size_t PL = (size_t)TBR * HH;  // gi plane stride (elements)

__device__ __forceinline__ float sigf(float x) { return 1.f / (1.f + __expf(-x)); }

// ---------------------------------------------------------------- k_prep ----
// Weight transposes to [n][k] f16 + per-(c,b) first-reset fr + bucket counts.
__global__ __launch_bounds__(256) void k_prep(
    const float* __restrict__ Wi, const float* __restrict__ Wh,
    const int* __restrict__ resets,
    f16* __restrict__ WiT, f16* __restrict__ WhT,
    int* __restrict__ fr, int* __restrict__ cnt) {
  int idx = blockIdx.x * 256 + threadIdx.x;
  if (idx < HH * H3) {
    int n = idx >> 9;         // output col 0..1535
    int k = idx & (HH - 1);   // 0..511
    WiT[idx] = (f16)Wi[(size_t)k * H3 + n];
    WhT[idx] = (f16)Wh[(size_t)k * H3 + n];
  }
  if (idx < NR) {
    int c = idx >> 7, b = idx & 127;
    int f = CL;
    for (int s = CL - 1; s >= 0; --s)
      if (resets[(c * CL + s) * BB + b]) f = s;
    fr[idx] = f;
    atomicAdd(&cnt[f], 1);    // cnt[0..8] bucket counts (pre-zeroed)
  }
}

// ---------------------------------------------------------------- k_sort ----
// st[f] = #rows with fr > f (descending-fr bucket starts). cnt layout:
// [0..8]=bc, [16..24]=st (st[s]=cnt_gt[s] for phase3), [32..40]=wk (scatter).
__global__ void k_sort(int* __restrict__ cnt) {
  int st = 0;
  cnt[16 + 8] = 0;
  for (int f = 7; f >= 0; --f) {
    st += cnt[f + 1];
    cnt[16 + f] = st;
  }
  for (int f = 1; f <= 8; ++f) cnt[32 + f] = cnt[16 + f];
}

__global__ __launch_bounds__(256) void k_scatter(
    const int* __restrict__ fr, int* __restrict__ cnt, int* __restrict__ list) {
  int idx = blockIdx.x * 256 + threadIdx.x;
  if (idx < NR) {
    int f = fr[idx];
    if (f >= 1) {
      int pos = atomicAdd(&cnt[32 + f], 1);
      list[pos] = idx;
    }
  }
}

// ------------------------------------------------------------- k_gemm_gi ----
// gi[plane p][i][jj] = sum_k x[i,k]*Wi[k, p*512+jj] + bi; 64x64 tile.
__global__ __launch_bounds__(256) void k_gemm_gi(
    const float* __restrict__ x, const f16* __restrict__ WiT,
    const float* __restrict__ bi, f16* __restrict__ gi) {
  __shared__ __align__(16) f16 As[64 * 48];
  __shared__ __align__(16) f16 Bs[64 * 48];
  const int tid = threadIdx.x;
  const int lane = tid & 63;
  const int w = tid >> 6;
  const int i0 = blockIdx.x * 64;
  const int j0 = blockIdx.y * 64;
  const int mw = (w & 1) * 32;
  const int nw = (w >> 1) * 32;

  f32x4 acc[2][2] = {};
  const int srow = tid >> 2;
  const int skp = (tid & 3) * 8;
  const int fr = lane & 15;
  const int fq8 = (lane >> 4) * 8;

  for (int kb = 0; kb < 16; ++kb) {
    const int k0 = kb * 32;
    const float* xp = x + (size_t)(i0 + srow) * HH + k0 + skp;
    float4 v0 = *(const float4*)xp;
    float4 v1 = *(const float4*)(xp + 4);
    f16x8 a8;
    a8[0] = (f16)v0.x; a8[1] = (f16)v0.y; a8[2] = (f16)v0.z; a8[3] = (f16)v0.w;
    a8[4] = (f16)v1.x; a8[5] = (f16)v1.y; a8[6] = (f16)v1.z; a8[7] = (f16)v1.w;
    *(f16x8*)&As[srow * 48 + skp] = a8;
    *(f16x8*)&Bs[srow * 48 + skp] =
        *(const f16x8*)(WiT + (size_t)(j0 + srow) * HH + k0 + skp);
    __syncthreads();
    f16x8 af0 = *(const f16x8*)&As[(mw + fr) * 48 + fq8];
    f16x8 af1 = *(const f16x8*)&As[(mw + 16 + fr) * 48 + fq8];
    f16x8 bf0 = *(const f16x8*)&Bs[(nw + fr) * 48 + fq8];
    f16x8 bf1 = *(const f16x8*)&Bs[(nw + 16 + fr) * 48 + fq8];
    acc[0][0] = __builtin_amdgcn_mfma_f32_16x16x32_f16(af0, bf0, acc[0][0], 0, 0, 0);
    acc[0][1] = __builtin_amdgcn_mfma_f32_16x16x32_f16(af0, bf1, acc[0][1], 0, 0, 0);
    acc[1][0] = __builtin_amdgcn_mfma_f32_16x16x32_f16(af1, bf0, acc[1][0], 0, 0, 0);
    acc[1][1] = __builtin_amdgcn_mfma_f32_16x16x32_f16(af1, bf1, acc[1][1], 0, 0, 0);
    __syncthreads();
  }
  const int trow = (lane >> 4) * 4;
  for (int mi = 0; mi < 2; ++mi)
    for (int ni = 0; ni < 2; ++ni)
      for (int r = 0; r < 4; ++r) {
        int row = mw + mi * 16 + trow + r;
        int col = nw + ni * 16 + fr;
        int j = j0 + col;                 // 0..1535
        int p = j >> 9, jj = j & 511;
        gi[(size_t)p * PL + (size_t)(i0 + row) * HH + jj] =
            (f16)(acc[mi][ni][r] + bi[j]);
      }
}

// ---------------------------------------------------------------- k_step0 ----
// Macro-step s=0: h_prev = 0 for all chunk-start rows -> elementwise gates.
// Writes out[t=c*8] (garbage for prefix rows, fixed by phase 3) and hA
// (zeroed where reset at s=1).
__global__ __launch_bounds__(256) void k_step0(
    const int* __restrict__ resets, const f16* __restrict__ gi,
    const float* __restrict__ bhn, float* __restrict__ out,
    f16* __restrict__ hA) {
  int gid = blockIdx.x * 256 + threadIdx.x;     // NR*64 units of 8
  int row = gid >> 6;                           // 0..8191 (c*128+b)
  int c8 = (gid & 63) * 8;
  int c = row >> 7, b = row & 127;
  size_t girow = (size_t)c * 1024 + b;          // t=c*8 -> t*128+b
  const f16x8 g0 = *(const f16x8*)(gi + girow * HH + c8);
  const f16x8 g1 = *(const f16x8*)(gi + PL + girow * HH + c8);
  const f16x8 g2 = *(const f16x8*)(gi + 2 * PL + girow * HH + c8);
  const int z1 = resets[(c * CL + 1) * BB + b];
  float4 o[2];
  f16x8 hn;
#pragma unroll
  for (int u = 0; u < 8; ++u) {
    float r = sigf((float)g0[u]);
    float z = sigf((float)g1[u]);
    float n = tanhf((float)g2[u] + r * bhn[c8 + u]);
    float h = (1.f - z) * n;
    ((float*)o)[u] = h;
    hn[u] = z1 ? (f16)0.f : (f16)h;
  }
  *(float4*)(out + girow * HH + c8) = o[0];
  *(float4*)(out + girow * HH + c8 + 4) = o[1];
  *(f16x8*)(hA + (size_t)row * HH + c8) = hn;
}

// --------------------------------------------------------------- k_phase1 ----
// Macro-step s (1..7): [8192x512] @ WhT[512x1536] (3 gates) + fused gates.
// Grid (64 chunks, 8 j-tiles of 64). Reads h from hrd, writes hwr (ping-pong
// to avoid same-launch RAW across j-tile blocks of the same chunk).
__global__ __launch_bounds__(256, 2) void k_phase1(
    int s, const int* __restrict__ resets, const f16* __restrict__ WhT,
    const f16* __restrict__ gi, const float* __restrict__ bhn,
    float* __restrict__ out, const f16* __restrict__ hrd,
    f16* __restrict__ hwr) {
  __shared__ __align__(16) f16 As[128 * 40];   // pad 40 halfs -> 2-way banks
  __shared__ __align__(16) f16 Bs[192 * 40];
  const int tid = threadIdx.x;
  const int lane = tid & 63;
  const int w = tid >> 6;
  const int c = blockIdx.x;
  const int j0 = blockIdx.y * 64;
  const int t = c * CL + s;
  const int wm = (w & 1) * 64;
  const int wn = (w >> 1) * 32;
  const int fr = lane & 15;
  const int q8 = (lane >> 4) * 8;

  f32x4 acc[3][4][2] = {};

  for (int kb = 0; kb < 16; ++kb) {
    const int k0 = kb * 32;
#pragma unroll
    for (int uu = 0; uu < 2; ++uu) {      // A: 128 rows x 4 octets
      int u = tid + uu * 256;
      int row = u >> 2, oc = (u & 3) * 8;
      *(f16x8*)&As[row * 40 + oc] =
          *(const f16x8*)(hrd + ((size_t)(c * BB + row)) * HH + k0 + oc);
    }
#pragma unroll
    for (int uu = 0; uu < 3; ++uu) {      // B: 192 rows (3 gates x 64 cols)
      int u = tid + uu * 256;
      int row = u >> 2, oc = (u & 3) * 8;
      int g = row >> 6, j = j0 + (row & 63);
      *(f16x8*)&Bs[row * 40 + oc] =
          *(const f16x8*)(WhT + ((size_t)(g * HH + j)) * HH + k0 + oc);
    }
    __syncthreads();
    f16x8 af[4];
#pragma unroll
    for (int mi = 0; mi < 4; ++mi)
      af[mi] = *(const f16x8*)&As[(wm + mi * 16 + fr) * 40 + q8];
    f16x8 bf[3][2];
#pragma unroll
    for (int g = 0; g < 3; ++g)
#pragma unroll
      for (int ni = 0; ni < 2; ++ni)
        bf[g][ni] = *(const f16x8*)&Bs[(g * 64 + wn + ni * 16 + fr) * 40 + q8];
#pragma unroll
    for (int g = 0; g < 3; ++g)
#pragma unroll
      for (int mi = 0; mi < 4; ++mi)
#pragma unroll
        for (int ni = 0; ni < 2; ++ni)
          acc[g][mi][ni] = __builtin_amdgcn_mfma_f32_16x16x32_f16(
              af[mi], bf[g][ni], acc[g][mi][ni], 0, 0, 0);
    __syncthreads();
  }

  const int trow = (lane >> 4) * 4;
#pragma unroll
  for (int mi = 0; mi < 4; ++mi)
#pragma unroll
    for (int ni = 0; ni < 2; ++ni) {
      const int j = j0 + wn + ni * 16 + fr;
      const float bh = bhn[j];
#pragma unroll
      for (int r = 0; r < 4; ++r) {
        const int b = wm + mi * 16 + trow + r;     // 0..127
        const size_t girow = (size_t)c * 1024 + (size_t)s * BB + b;
        const float gr = (float)gi[girow * HH + j];
        const float gz = (float)gi[PL + girow * HH + j];
        const float gn = (float)gi[2 * PL + girow * HH + j];
        const float hp = (float)hrd[((size_t)(c * BB + b)) * HH + j];
        const float rr = sigf(gr + acc[0][mi][ni][r]);
        const float zz = sigf(gz + acc[1][mi][ni][r]);
        const float nn = tanhf(gn + rr * (acc[2][mi][ni][r] + bh));
        const float hnew = (1.f - zz) * nn + zz * hp;
        out[girow * HH + j] = hnew;
        int zr = (s < 7) ? resets[(t + 1) * BB + b] : 0;
        hwr[((size_t)(c * BB + b)) * HH + j] = zr ? (f16)0.f : (f16)hnew;
      }
    }
}

// ---------------------------------------------------------------- k_bound ----
// Parallel chunk-boundary fill: hin[c] = (f16)h0 (c==0) or hend[c-1] when
// chunk c-1 is sealed (contains a reset -> its exit state is exact).
// Rows whose predecessor is transparent are left for k_chain.
__global__ __launch_bounds__(256) void k_bound(
    const int* __restrict__ fr, const f16* __restrict__ hend,
    const float* __restrict__ h0, f16* __restrict__ hin) {
  int gid = blockIdx.x * 256 + threadIdx.x;     // NR*64 units of 8
  int row = gid >> 6;                           // c*128+b
  int o8 = (gid & 63) * 8;
  int c = row >> 7, b = row & 127;
  if (c == 0) {
    const float* hp = h0 + (size_t)b * HH + o8;
    float4 v0 = *(const float4*)hp;
    float4 v1 = *(const float4*)(hp + 4);
    f16x8 h;
    h[0] = (f16)v0.x; h[1] = (f16)v0.y; h[2] = (f16)v0.z; h[3] = (f16)v0.w;
    h[4] = (f16)v1.x; h[5] = (f16)v1.y; h[6] = (f16)v1.z; h[7] = (f16)v1.w;
    *(f16x8*)(hin + (size_t)row * HH + o8) = h;
  } else if (fr[row - BB] < CL) {
    *(f16x8*)(hin + (size_t)row * HH + o8) =
        *(const f16x8*)(hend + (size_t)(row - BB) * HH + o8);
  }
}

// ---------------------------------------------------------------- k_chain ----
// Transparent-run propagation. One block per candidate (c,b); survives only
// at run starts (fr[c]==8 and predecessor sealed/absent) — ~32 of 8192.
// Per GRU step: wave-per-row matvec. Lane l holds hs[l*8..+8] in registers;
// each wave computes rows n = r*4 + w via one coalesced 1KB row load
// (f16x8 per lane), 8 FMAs, and a 6-round shfl_xor reduction. Rows unrolled
// x2 for ILP. Writes hin[c+1]; continues while successor also transparent.
// Does NOT write `out` — phase 3 covers all positions of fr==8 rows.
__global__ __launch_bounds__(256) void k_chain(
    const int* __restrict__ fr, const f16* __restrict__ hend,
    const f16* __restrict__ WhT, const f16* __restrict__ gi,
    const float* __restrict__ bhn, const float* __restrict__ h0,
    f16* __restrict__ hin) {
  const int row0 = blockIdx.x;                  // c0*128+b
  const int c0 = row0 >> 7, b = row0 & 127;
  if (fr[row0] != CL) return;                   // not transparent
  if (c0 > 0 && fr[row0 - BB] == CL) return;    // mid-run, handled by starter
  if (c0 == NC - 1) return;                     // no successor needs h_exit

  __shared__ float hs[HH];
  __shared__ float gh[H3];
  const int tid = threadIdx.x;
  const int lane = tid & 63;
  const int w = tid >> 6;
  if (c0 == 0) {
    for (int i = tid; i < HH; i += 256) hs[i] = h0[(size_t)b * HH + i];
  } else {
    for (int i = tid; i < HH; i += 256)
      hs[i] = (float)hend[(size_t)(row0 - BB) * HH + i];
  }
  __syncthreads();

  int c = c0;
  while (c < NC - 1) {
    for (int s = 0; s < CL; ++s) {
      const size_t girow = (size_t)(c * CL + s) * BB + b;
      // h fragment for this lane, once per step (reused for all rows)
      float hv[8];
      {
        float4 h0v = *(const float4*)&hs[lane * 8];
        float4 h1v = *(const float4*)&hs[lane * 8 + 4];
        hv[0] = h0v.x; hv[1] = h0v.y; hv[2] = h0v.z; hv[3] = h0v.w;
        hv[4] = h1v.x; hv[5] = h1v.y; hv[6] = h1v.z; hv[7] = h1v.w;
      }
      // gh[n] = sum_k WhT[n][k]*hs[k]; wave w covers rows n = r*4 + w
      for (int r = 0; r < H3 / 4; r += 2) {
        const int n0 = r * 4 + w;
        const int n1 = n0 + 4;
        f16x8 w0 = *(const f16x8*)(WhT + (size_t)n0 * HH + lane * 8);
        f16x8 w1 = *(const f16x8*)(WhT + (size_t)n1 * HH + lane * 8);
        float a0 = 0.f, a1 = 0.f;
#pragma unroll
        for (int u = 0; u < 8; ++u) {
          a0 += (float)w0[u] * hv[u];
          a1 += (float)w1[u] * hv[u];
        }
#pragma unroll
        for (int d = 32; d >= 1; d >>= 1) {
          a0 += __shfl_xor(a0, d, 64);
          a1 += __shfl_xor(a1, d, 64);
        }
        if (lane == 0) {
          gh[n0] = a0;
          gh[n1] = a1;
        }
      }
      __syncthreads();
      for (int j = tid; j < HH; j += 256) {
        const float rr = sigf((float)gi[girow * HH + j] + gh[j]);
        const float zz = sigf((float)gi[PL + girow * HH + j] + gh[HH + j]);
        const float nn =
            tanhf((float)gi[2 * PL + girow * HH + j] + rr * (gh[2 * HH + j] + bhn[j]));
        hs[j] = (1.f - zz) * nn + zz * hs[j];
      }
      __syncthreads();
    }
    const int nrow = (c + 1) * BB + b;
    for (int i = tid; i < HH; i += 256)
      hin[(size_t)nrow * HH + i] = (f16)hs[i];
    if (fr[nrow] != CL) break;   // successor sealed: chain cut
    ++c;                         // successor transparent: keep propagating
  }
}

// --------------------------------------------------------------- k_phase3 ----
// Prefix fixup, launch per s: rows with fr > s (first cnt_gt[s] of fr-sorted
// list). 16 gathered rows per block; full 3-gate GEMM vs WhT from L2.
__global__ __launch_bounds__(256) void k_phase3(
    int s, const int* __restrict__ cnt, const int* __restrict__ list,
    const f16* __restrict__ WhT, const f16* __restrict__ gi,
    const float* __restrict__ bhn, float* __restrict__ out,
    f16* __restrict__ hph) {
  const int count = cnt[16 + s];
  const int r0 = blockIdx.x * 16;
  if (r0 >= count) return;
  __shared__ __align__(16) f16 As[16 * 520];
  __shared__ int rows[16];
  const int tid = threadIdx.x;
  const int lane = tid & 63;
  const int w = tid >> 6;
  if (tid < 16) rows[tid] = (r0 + tid < count) ? list[r0 + tid] : -1;
  __syncthreads();
#pragma unroll
  for (int uu = 0; uu < 4; ++uu) {
    int u = tid + uu * 256;
    int row = u >> 6, oc = (u & 63) * 8;
    int rid = rows[row];
    f16x8 v = {};
    if (rid >= 0) v = *(const f16x8*)(hph + (size_t)rid * HH + oc);
    *(f16x8*)&As[row * 520 + oc] = v;
  }
  __syncthreads();
  const int fr16 = lane & 15;
  const int q8 = (lane >> 4) * 8;
  const int trow = (lane >> 4) * 4;
  for (int jt = 0; jt < 8; ++jt) {
    const int jb = w * 128 + jt * 16;
    f32x4 a0 = {}, a1 = {}, a2 = {};
#pragma unroll 4
    for (int kb = 0; kb < 16; ++kb) {
      const int k0 = kb * 32;
      f16x8 af = *(const f16x8*)&As[fr16 * 520 + k0 + q8];
      f16x8 b0 = *(const f16x8*)(WhT + ((size_t)(jb + fr16)) * HH + k0 + q8);
      f16x8 b1 = *(const f16x8*)(WhT + ((size_t)(HH + jb + fr16)) * HH + k0 + q8);
      f16x8 b2 = *(const f16x8*)(WhT + ((size_t)(2 * HH + jb + fr16)) * HH + k0 + q8);
      a0 = __builtin_amdgcn_mfma_f32_16x16x32_f16(af, b0, a0, 0, 0, 0);
      a1 = __builtin_amdgcn_mfma_f32_16x16x32_f16(af, b1, a1, 0, 0, 0);
      a2 = __builtin_amdgcn_mfma_f32_16x16x32_f16(af, b2, a2, 0, 0, 0);
    }
    const int j = jb + fr16;
    const float bh = bhn[j];
#pragma unroll
    for (int r = 0; r < 4; ++r) {
      const int rid = rows[trow + r];
      if (rid < 0) continue;
      const int c = rid >> 7, b = rid & 127;
      const size_t girow = (size_t)(c * CL + s) * BB + b;
      const float gr = (float)gi[girow * HH + j];
      const float gz = (float)gi[PL + girow * HH + j];
      const float gn = (float)gi[2 * PL + girow * HH + j];
      const float hp = (float)hph[(size_t)rid * HH + j];
      const float rr = sigf(gr + a0[r]);
      const float zz = sigf(gz + a1[r]);
      const float nn = tanhf(gn + rr * (a2[r] + bh));
      const float hnew = (1.f - zz) * nn + zz * hp;
      out[girow * HH + j] = hnew;
      hph[(size_t)rid * HH + j] = (f16)hnew;
    }
  }
}

// ---------------------------------------------------------------------------
extern "C" void kernel_launch(void* const* d_in, const int* in_sizes, int n_in,
                              void* d_out, int out_size, void* d_ws, size_t ws_size,
                              hipStream_t stream) {
  const float* x = (const float*)d_in[0];
  const int* resets = (const int*)d_in[1];
  const float* Wi = (const float*)d_in[2];
  const float* bi = (const float*)d_in[3];
  const float* Wh = (const float*)d_in[4];
  const float* bhn = (const float*)d_in[5];
  const float* h0 = (const float*)d_in[6];
  float* out = (float*)d_out;

  char* ws = (char*)d_ws;
  size_t off = 0;
  f16* gi = (f16*)(ws + off);   off += 3 * PL * sizeof(f16);            // 201.3 MB
  f16* WiT = (f16*)(ws + off);  off += (size_t)HH * H3 * sizeof(f16);
  f16* WhT = (f16*)(ws + off);  off += (size_t)HH * H3 * sizeof(f16);
  f16* hA = (f16*)(ws + off);   off += (size_t)NR * HH * sizeof(f16);   // 8.4 MB
  f16* hB = (f16*)(ws + off);   off += (size_t)NR * HH * sizeof(f16);
  f16* hin = (f16*)(ws + off);  off += (size_t)NR * HH * sizeof(f16);
  int* fr = (int*)(ws + off);   off += NR * sizeof(int);
  int* list = (int*)(ws + off); off += NR * sizeof(int);
  int* cnt = (int*)(ws + off);  off += 64 * sizeof(int);
  (void)ws_size; (void)in_sizes; (void)n_in; (void)out_size;

  hipMemsetAsync(cnt, 0, 64 * sizeof(int), stream);
  k_prep<<<dim3(3072), 256, 0, stream>>>(Wi, Wh, resets, WiT, WhT, fr, cnt);
  k_sort<<<dim3(1), 1, 0, stream>>>(cnt);
  k_scatter<<<dim3(32), 256, 0, stream>>>(fr, cnt, list);
  k_gemm_gi<<<dim3(TBR / 64, H3 / 64), 256, 0, stream>>>(x, WiT, bi, gi);
  k_step0<<<dim3(NR * 64 / 256), 256, 0, stream>>>(resets, gi, bhn, out, hA);
  // phase 1: s=1..7; ping-pong: s odd reads hA writes hB, s even reads hB
  for (int s = 1; s < CL; ++s) {
    const f16* hrd = (s & 1) ? hA : hB;
    f16* hwr = (s & 1) ? hB : hA;
    k_phase1<<<dim3(NC, 8), 256, 0, stream>>>(s, resets, WhT, gi, bhn, out, hrd, hwr);
  }
  // chunk-end h = buffer written at s=7 (odd) = hB
  k_bound<<<dim3(NR * 64 / 256), 256, 0, stream>>>(fr, hB, h0, hin);
  k_chain<<<dim3(NR), 256, 0, stream>>>(fr, hB, WhT, gi, bhn, h0, hin);
  for (int s = 0; s < CL; ++s)
    k_phase3<<<dim3(NR / 16), 256, 0, stream>>>(s, cnt, list, WhT, gi, bhn, out, hin);
}

// Round 3
// 2044.767 us; speedup vs baseline: 1.3987x; 1.3987x over previous
//
#include <hip/hip_runtime.h>

// ScannedRNN (flax GRUCell with per-step carry reset), T=512, B=128, H=512.
// R5: throughput-shaped chain matvec. R4 was latency-serialized (1 wave/SIMD,
// 6-round shfl chain per row). Now k_chain uses 1024 threads (16 waves,
// 4/SIMD TLP); each wave owns 96 contiguous WhT rows (coalesced 1KB loads,
// unroll-8 => 8 loads in flight); reduction is 3 shfl_xor rounds (64->8
// lanes) + LDS partial dump (transposed, conflict-free) + tiny pass-2 sum;
// per-step gi gate values prefetched into registers before the matvec.
// Per-step floor = WhT stream 1.57MB from L2 @ ~60B/cy/CU ~= 11 us.
// Everything else unchanged from R3/R4 (sealed-chunk cut, k_bound, phase3).

typedef _Float16 f16;
typedef _Float16 f16x8 __attribute__((ext_vector_type(8)));
typedef float f32x4 __attribute__((ext_vector_type(4)));

#define TT 512
#define BB 128
#define HH 512
#define H3 1536
#define TBR 65536                     // TT*BB rows
#define NC 64                         // chunks
#define CL 8                          // chunk length
#define NR 8192                       // NC*BB rows of chunk-state
static const size_t PL = (size_t)TBR * HH;  // gi plane stride (elements)

__device__ __forceinline__ float sigf(float x) { return 1.f / (1.f + __expf(-x)); }

// ---------------------------------------------------------------- k_prep ----
// Weight transposes to [n][k] f16 + per-(c,b) first-reset fr + bucket counts.
__global__ __launch_bounds__(256) void k_prep(
    const float* __restrict__ Wi, const float* __restrict__ Wh,
    const int* __restrict__ resets,
    f16* __restrict__ WiT, f16* __restrict__ WhT,
    int* __restrict__ fr, int* __restrict__ cnt) {
  int idx = blockIdx.x * 256 + threadIdx.x;
  if (idx < HH * H3) {
    int n = idx >> 9;         // output col 0..1535
    int k = idx & (HH - 1);   // 0..511
    WiT[idx] = (f16)Wi[(size_t)k * H3 + n];
    WhT[idx] = (f16)Wh[(size_t)k * H3 + n];
  }
  if (idx < NR) {
    int c = idx >> 7, b = idx & 127;
    int f = CL;
    for (int s = CL - 1; s >= 0; --s)
      if (resets[(c * CL + s) * BB + b]) f = s;
    fr[idx] = f;
    atomicAdd(&cnt[f], 1);    // cnt[0..8] bucket counts (pre-zeroed)
  }
}

// ---------------------------------------------------------------- k_sort ----
// st[f] = #rows with fr > f (descending-fr bucket starts). cnt layout:
// [0..8]=bc, [16..24]=st (st[s]=cnt_gt[s] for phase3), [32..40]=wk (scatter).
__global__ void k_sort(int* __restrict__ cnt) {
  int st = 0;
  cnt[16 + 8] = 0;
  for (int f = 7; f >= 0; --f) {
    st += cnt[f + 1];
    cnt[16 + f] = st;
  }
  for (int f = 1; f <= 8; ++f) cnt[32 + f] = cnt[16 + f];
}

__global__ __launch_bounds__(256) void k_scatter(
    const int* __restrict__ fr, int* __restrict__ cnt, int* __restrict__ list) {
  int idx = blockIdx.x * 256 + threadIdx.x;
  if (idx < NR) {
    int f = fr[idx];
    if (f >= 1) {
      int pos = atomicAdd(&cnt[32 + f], 1);
      list[pos] = idx;
    }
  }
}

// ------------------------------------------------------------- k_gemm_gi ----
// gi[plane p][i][jj] = sum_k x[i,k]*Wi[k, p*512+jj] + bi; 64x64 tile.
__global__ __launch_bounds__(256) void k_gemm_gi(
    const float* __restrict__ x, const f16* __restrict__ WiT,
    const float* __restrict__ bi, f16* __restrict__ gi) {
  __shared__ __align__(16) f16 As[64 * 48];
  __shared__ __align__(16) f16 Bs[64 * 48];
  const int tid = threadIdx.x;
  const int lane = tid & 63;
  const int w = tid >> 6;
  const int i0 = blockIdx.x * 64;
  const int j0 = blockIdx.y * 64;
  const int mw = (w & 1) * 32;
  const int nw = (w >> 1) * 32;

  f32x4 acc[2][2] = {};
  const int srow = tid >> 2;
  const int skp = (tid & 3) * 8;
  const int fr = lane & 15;
  const int fq8 = (lane >> 4) * 8;

  for (int kb = 0; kb < 16; ++kb) {
    const int k0 = kb * 32;
    const float* xp = x + (size_t)(i0 + srow) * HH + k0 + skp;
    float4 v0 = *(const float4*)xp;
    float4 v1 = *(const float4*)(xp + 4);
    f16x8 a8;
    a8[0] = (f16)v0.x; a8[1] = (f16)v0.y; a8[2] = (f16)v0.z; a8[3] = (f16)v0.w;
    a8[4] = (f16)v1.x; a8[5] = (f16)v1.y; a8[6] = (f16)v1.z; a8[7] = (f16)v1.w;
    *(f16x8*)&As[srow * 48 + skp] = a8;
    *(f16x8*)&Bs[srow * 48 + skp] =
        *(const f16x8*)(WiT + (size_t)(j0 + srow) * HH + k0 + skp);
    __syncthreads();
    f16x8 af0 = *(const f16x8*)&As[(mw + fr) * 48 + fq8];
    f16x8 af1 = *(const f16x8*)&As[(mw + 16 + fr) * 48 + fq8];
    f16x8 bf0 = *(const f16x8*)&Bs[(nw + fr) * 48 + fq8];
    f16x8 bf1 = *(const f16x8*)&Bs[(nw + 16 + fr) * 48 + fq8];
    acc[0][0] = __builtin_amdgcn_mfma_f32_16x16x32_f16(af0, bf0, acc[0][0], 0, 0, 0);
    acc[0][1] = __builtin_amdgcn_mfma_f32_16x16x32_f16(af0, bf1, acc[0][1], 0, 0, 0);
    acc[1][0] = __builtin_amdgcn_mfma_f32_16x16x32_f16(af1, bf0, acc[1][0], 0, 0, 0);
    acc[1][1] = __builtin_amdgcn_mfma_f32_16x16x32_f16(af1, bf1, acc[1][1], 0, 0, 0);
    __syncthreads();
  }
  const int trow = (lane >> 4) * 4;
  for (int mi = 0; mi < 2; ++mi)
    for (int ni = 0; ni < 2; ++ni)
      for (int r = 0; r < 4; ++r) {
        int row = mw + mi * 16 + trow + r;
        int col = nw + ni * 16 + fr;
        int j = j0 + col;                 // 0..1535
        int p = j >> 9, jj = j & 511;
        gi[(size_t)p * PL + (size_t)(i0 + row) * HH + jj] =
            (f16)(acc[mi][ni][r] + bi[j]);
      }
}

// ---------------------------------------------------------------- k_step0 ----
// Macro-step s=0: h_prev = 0 for all chunk-start rows -> elementwise gates.
// Writes out[t=c*8] (garbage for prefix rows, fixed by phase 3) and hA
// (zeroed where reset at s=1).
__global__ __launch_bounds__(256) void k_step0(
    const int* __restrict__ resets, const f16* __restrict__ gi,
    const float* __restrict__ bhn, float* __restrict__ out,
    f16* __restrict__ hA) {
  int gid = blockIdx.x * 256 + threadIdx.x;     // NR*64 units of 8
  int row = gid >> 6;                           // 0..8191 (c*128+b)
  int c8 = (gid & 63) * 8;
  int c = row >> 7, b = row & 127;
  size_t girow = (size_t)c * 1024 + b;          // t=c*8 -> t*128+b
  const f16x8 g0 = *(const f16x8*)(gi + girow * HH + c8);
  const f16x8 g1 = *(const f16x8*)(gi + PL + girow * HH + c8);
  const f16x8 g2 = *(const f16x8*)(gi + 2 * PL + girow * HH + c8);
  const int z1 = resets[(c * CL + 1) * BB + b];
  float4 o[2];
  f16x8 hn;
#pragma unroll
  for (int u = 0; u < 8; ++u) {
    float r = sigf((float)g0[u]);
    float z = sigf((float)g1[u]);
    float n = tanhf((float)g2[u] + r * bhn[c8 + u]);
    float h = (1.f - z) * n;
    ((float*)o)[u] = h;
    hn[u] = z1 ? (f16)0.f : (f16)h;
  }
  *(float4*)(out + girow * HH + c8) = o[0];
  *(float4*)(out + girow * HH + c8 + 4) = o[1];
  *(f16x8*)(hA + (size_t)row * HH + c8) = hn;
}

// --------------------------------------------------------------- k_phase1 ----
// Macro-step s (1..7): [8192x512] @ WhT[512x1536] (3 gates) + fused gates.
// Grid (64 chunks, 8 j-tiles of 64). Reads h from hrd, writes hwr (ping-pong
// to avoid same-launch RAW across j-tile blocks of the same chunk).
__global__ __launch_bounds__(256, 2) void k_phase1(
    int s, const int* __restrict__ resets, const f16* __restrict__ WhT,
    const f16* __restrict__ gi, const float* __restrict__ bhn,
    float* __restrict__ out, const f16* __restrict__ hrd,
    f16* __restrict__ hwr) {
  __shared__ __align__(16) f16 As[128 * 40];   // pad 40 halfs -> 2-way banks
  __shared__ __align__(16) f16 Bs[192 * 40];
  const int tid = threadIdx.x;
  const int lane = tid & 63;
  const int w = tid >> 6;
  const int c = blockIdx.x;
  const int j0 = blockIdx.y * 64;
  const int t = c * CL + s;
  const int wm = (w & 1) * 64;
  const int wn = (w >> 1) * 32;
  const int fr = lane & 15;
  const int q8 = (lane >> 4) * 8;

  f32x4 acc[3][4][2] = {};

  for (int kb = 0; kb < 16; ++kb) {
    const int k0 = kb * 32;
#pragma unroll
    for (int uu = 0; uu < 2; ++uu) {      // A: 128 rows x 4 octets
      int u = tid + uu * 256;
      int row = u >> 2, oc = (u & 3) * 8;
      *(f16x8*)&As[row * 40 + oc] =
          *(const f16x8*)(hrd + ((size_t)(c * BB + row)) * HH + k0 + oc);
    }
#pragma unroll
    for (int uu = 0; uu < 3; ++uu) {      // B: 192 rows (3 gates x 64 cols)
      int u = tid + uu * 256;
      int row = u >> 2, oc = (u & 3) * 8;
      int g = row >> 6, j = j0 + (row & 63);
      *(f16x8*)&Bs[row * 40 + oc] =
          *(const f16x8*)(WhT + ((size_t)(g * HH + j)) * HH + k0 + oc);
    }
    __syncthreads();
    f16x8 af[4];
#pragma unroll
    for (int mi = 0; mi < 4; ++mi)
      af[mi] = *(const f16x8*)&As[(wm + mi * 16 + fr) * 40 + q8];
    f16x8 bf[3][2];
#pragma unroll
    for (int g = 0; g < 3; ++g)
#pragma unroll
      for (int ni = 0; ni < 2; ++ni)
        bf[g][ni] = *(const f16x8*)&Bs[(g * 64 + wn + ni * 16 + fr) * 40 + q8];
#pragma unroll
    for (int g = 0; g < 3; ++g)
#pragma unroll
      for (int mi = 0; mi < 4; ++mi)
#pragma unroll
        for (int ni = 0; ni < 2; ++ni)
          acc[g][mi][ni] = __builtin_amdgcn_mfma_f32_16x16x32_f16(
              af[mi], bf[g][ni], acc[g][mi][ni], 0, 0, 0);
    __syncthreads();
  }

  const int trow = (lane >> 4) * 4;
#pragma unroll
  for (int mi = 0; mi < 4; ++mi)
#pragma unroll
    for (int ni = 0; ni < 2; ++ni) {
      const int j = j0 + wn + ni * 16 + fr;
      const float bh = bhn[j];
#pragma unroll
      for (int r = 0; r < 4; ++r) {
        const int b = wm + mi * 16 + trow + r;     // 0..127
        const size_t girow = (size_t)c * 1024 + (size_t)s * BB + b;
        const float gr = (float)gi[girow * HH + j];
        const float gz = (float)gi[PL + girow * HH + j];
        const float gn = (float)gi[2 * PL + girow * HH + j];
        const float hp = (float)hrd[((size_t)(c * BB + b)) * HH + j];
        const float rr = sigf(gr + acc[0][mi][ni][r]);
        const float zz = sigf(gz + acc[1][mi][ni][r]);
        const float nn = tanhf(gn + rr * (acc[2][mi][ni][r] + bh));
        const float hnew = (1.f - zz) * nn + zz * hp;
        out[girow * HH + j] = hnew;
        int zr = (s < 7) ? resets[(t + 1) * BB + b] : 0;
        hwr[((size_t)(c * BB + b)) * HH + j] = zr ? (f16)0.f : (f16)hnew;
      }
    }
}

// ---------------------------------------------------------------- k_bound ----
// Parallel chunk-boundary fill: hin[c] = (f16)h0 (c==0) or hend[c-1] when
// chunk c-1 is sealed (contains a reset -> its exit state is exact).
// Rows whose predecessor is transparent are left for k_chain.
__global__ __launch_bounds__(256) void k_bound(
    const int* __restrict__ fr, const f16* __restrict__ hend,
    const float* __restrict__ h0, f16* __restrict__ hin) {
  int gid = blockIdx.x * 256 + threadIdx.x;     // NR*64 units of 8
  int row = gid >> 6;                           // c*128+b
  int o8 = (gid & 63) * 8;
  int c = row >> 7, b = row & 127;
  if (c == 0) {
    const float* hp = h0 + (size_t)b * HH + o8;
    float4 v0 = *(const float4*)hp;
    float4 v1 = *(const float4*)(hp + 4);
    f16x8 h;
    h[0] = (f16)v0.x; h[1] = (f16)v0.y; h[2] = (f16)v0.z; h[3] = (f16)v0.w;
    h[4] = (f16)v1.x; h[5] = (f16)v1.y; h[6] = (f16)v1.z; h[7] = (f16)v1.w;
    *(f16x8*)(hin + (size_t)row * HH + o8) = h;
  } else if (fr[row - BB] < CL) {
    *(f16x8*)(hin + (size_t)row * HH + o8) =
        *(const f16x8*)(hend + (size_t)(row - BB) * HH + o8);
  }
}

// ---------------------------------------------------------------- k_chain ----
// Transparent-run propagation, throughput-shaped. One block per candidate
// (c,b); survives only at run starts (~32 of 8192). 1024 threads = 16 waves
// (4/SIMD TLP). Per GRU step:
//   - prefetch this step's gi gate values into registers (hides HBM latency
//     under the weight stream);
//   - wave w computes rows [w*96, (w+1)*96): lane l loads WhT[n][l*8..+8]
//     (coalesced 1KB/instr, unroll-8 keeps 8 loads in flight), 8 cvt+FMA,
//     3 shfl_xor rounds reduce 64->8 lanes, dump 8 partials to LDS
//     part[8][1536] (transposed -> conflict-free pass-2);
//   - pass 2: gh[n] = sum of 8 partials; then 512-thread gate update.
// Writes hin[c+1]; continues while successor also transparent. Does NOT
// write `out` — phase 3 covers all positions of fr==8 rows.
__global__ __launch_bounds__(1024) void k_chain(
    const int* __restrict__ fr, const f16* __restrict__ hend,
    const f16* __restrict__ WhT, const f16* __restrict__ gi,
    const float* __restrict__ bhn, const float* __restrict__ h0,
    f16* __restrict__ hin) {
  const int row0 = blockIdx.x;                  // c0*128+b
  const int c0 = row0 >> 7, b = row0 & 127;
  if (fr[row0] != CL) return;                   // not transparent
  if (c0 > 0 && fr[row0 - BB] == CL) return;    // mid-run, handled by starter
  if (c0 == NC - 1) return;                     // no successor needs h_exit

  __shared__ float hs[HH];                      // 2 KB
  __shared__ float gh[H3];                      // 6 KB
  __shared__ float part[8 * H3];                // 48 KB, [u][n] transposed
  const int tid = threadIdx.x;
  const int lane = tid & 63;
  const int w = tid >> 6;                       // 0..15
  if (c0 == 0) {
    for (int i = tid; i < HH; i += 1024) hs[i] = h0[(size_t)b * HH + i];
  } else {
    for (int i = tid; i < HH; i += 1024)
      hs[i] = (float)hend[(size_t)(row0 - BB) * HH + i];
  }
  __syncthreads();

  int c = c0;
  while (c < NC - 1) {
    for (int s = 0; s < CL; ++s) {
      const size_t girow = (size_t)(c * CL + s) * BB + b;
      // prefetch gate inputs for this step (independent of matvec)
      float gr_v = 0.f, gz_v = 0.f, gn_v = 0.f, hp_v = 0.f, bh_v = 0.f;
      if (tid < HH) {
        gr_v = (float)gi[girow * HH + tid];
        gz_v = (float)gi[PL + girow * HH + tid];
        gn_v = (float)gi[2 * PL + girow * HH + tid];
        bh_v = bhn[tid];
        hp_v = hs[tid];
      }
      // lane's h fragment (same mapping for every wave)
      float hv[8];
      {
        float4 h0v = *(const float4*)&hs[lane * 8];
        float4 h1v = *(const float4*)&hs[lane * 8 + 4];
        hv[0] = h0v.x; hv[1] = h0v.y; hv[2] = h0v.z; hv[3] = h0v.w;
        hv[4] = h1v.x; hv[5] = h1v.y; hv[6] = h1v.z; hv[7] = h1v.w;
      }
      // gh[n] = sum_k WhT[n][k]*hs[k]; wave w owns rows [w*96, (w+1)*96)
      const f16* wp = WhT + (size_t)(w * 96) * HH + lane * 8;
#pragma unroll 8
      for (int r = 0; r < 96; ++r) {
        f16x8 wv = *(const f16x8*)(wp + (size_t)r * HH);
        float a = 0.f;
#pragma unroll
        for (int u = 0; u < 8; ++u) a += (float)wv[u] * hv[u];
        a += __shfl_xor(a, 32, 64);
        a += __shfl_xor(a, 16, 64);
        a += __shfl_xor(a, 8, 64);
        if (lane < 8) part[lane * H3 + (w * 96 + r)] = a;
      }
      __syncthreads();
      for (int n = tid; n < H3; n += 1024) {
        float a = part[n];
#pragma unroll
        for (int u = 1; u < 8; ++u) a += part[u * H3 + n];
        gh[n] = a;
      }
      __syncthreads();
      if (tid < HH) {
        const int j = tid;
        const float rr = sigf(gr_v + gh[j]);
        const float zz = sigf(gz_v + gh[HH + j]);
        const float nn = tanhf(gn_v + rr * (gh[2 * HH + j] + bh_v));
        hs[j] = (1.f - zz) * nn + zz * hp_v;
      }
      __syncthreads();
    }
    const int nrow = (c + 1) * BB + b;
    for (int i = tid; i < HH; i += 1024)
      hin[(size_t)nrow * HH + i] = (f16)hs[i];
    if (fr[nrow] != CL) break;   // successor sealed: chain cut
    ++c;                         // successor transparent: keep propagating
  }
}

// --------------------------------------------------------------- k_phase3 ----
// Prefix fixup, launch per s: rows with fr > s (first cnt_gt[s] of fr-sorted
// list). 16 gathered rows per block; full 3-gate GEMM vs WhT from L2.
__global__ __launch_bounds__(256) void k_phase3(
    int s, const int* __restrict__ cnt, const int* __restrict__ list,
    const f16* __restrict__ WhT, const f16* __restrict__ gi,
    const float* __restrict__ bhn, float* __restrict__ out,
    f16* __restrict__ hph) {
  const int count = cnt[16 + s];
  const int r0 = blockIdx.x * 16;
  if (r0 >= count) return;
  __shared__ __align__(16) f16 As[16 * 520];
  __shared__ int rows[16];
  const int tid = threadIdx.x;
  const int lane = tid & 63;
  const int w = tid >> 6;
  if (tid < 16) rows[tid] = (r0 + tid < count) ? list[r0 + tid] : -1;
  __syncthreads();
#pragma unroll
  for (int uu = 0; uu < 4; ++uu) {
    int u = tid + uu * 256;
    int row = u >> 6, oc = (u & 63) * 8;
    int rid = rows[row];
    f16x8 v = {};
    if (rid >= 0) v = *(const f16x8*)(hph + (size_t)rid * HH + oc);
    *(f16x8*)&As[row * 520 + oc] = v;
  }
  __syncthreads();
  const int fr16 = lane & 15;
  const int q8 = (lane >> 4) * 8;
  const int trow = (lane >> 4) * 4;
  for (int jt = 0; jt < 8; ++jt) {
    const int jb = w * 128 + jt * 16;
    f32x4 a0 = {}, a1 = {}, a2 = {};
#pragma unroll 4
    for (int kb = 0; kb < 16; ++kb) {
      const int k0 = kb * 32;
      f16x8 af = *(const f16x8*)&As[fr16 * 520 + k0 + q8];
      f16x8 b0 = *(const f16x8*)(WhT + ((size_t)(jb + fr16)) * HH + k0 + q8);
      f16x8 b1 = *(const f16x8*)(WhT + ((size_t)(HH + jb + fr16)) * HH + k0 + q8);
      f16x8 b2 = *(const f16x8*)(WhT + ((size_t)(2 * HH + jb + fr16)) * HH + k0 + q8);
      a0 = __builtin_amdgcn_mfma_f32_16x16x32_f16(af, b0, a0, 0, 0, 0);
      a1 = __builtin_amdgcn_mfma_f32_16x16x32_f16(af, b1, a1, 0, 0, 0);
      a2 = __builtin_amdgcn_mfma_f32_16x16x32_f16(af, b2, a2, 0, 0, 0);
    }
    const int j = jb + fr16;
    const float bh = bhn[j];
#pragma unroll
    for (int r = 0; r < 4; ++r) {
      const int rid = rows[trow + r];
      if (rid < 0) continue;
      const int c = rid >> 7, b = rid & 127;
      const size_t girow = (size_t)(c * CL + s) * BB + b;
      const float gr = (float)gi[girow * HH + j];
      const float gz = (float)gi[PL + girow * HH + j];
      const float gn = (float)gi[2 * PL + girow * HH + j];
      const float hp = (float)hph[(size_t)rid * HH + j];
      const float rr = sigf(gr + a0[r]);
      const float zz = sigf(gz + a1[r]);
      const float nn = tanhf(gn + rr * (a2[r] + bh));
      const float hnew = (1.f - zz) * nn + zz * hp;
      out[girow * HH + j] = hnew;
      hph[(size_t)rid * HH + j] = (f16)hnew;
    }
  }
}

// ---------------------------------------------------------------------------
extern "C" void kernel_launch(void* const* d_in, const int* in_sizes, int n_in,
                              void* d_out, int out_size, void* d_ws, size_t ws_size,
                              hipStream_t stream) {
  const float* x = (const float*)d_in[0];
  const int* resets = (const int*)d_in[1];
  const float* Wi = (const float*)d_in[2];
  const float* bi = (const float*)d_in[3];
  const float* Wh = (const float*)d_in[4];
  const float* bhn = (const float*)d_in[5];
  const float* h0 = (const float*)d_in[6];
  float* out = (float*)d_out;

  char* ws = (char*)d_ws;
  size_t off = 0;
  f16* gi = (f16*)(ws + off);   off += 3 * PL * sizeof(f16);            // 201.3 MB
  f16* WiT = (f16*)(ws + off);  off += (size_t)HH * H3 * sizeof(f16);
  f16* WhT = (f16*)(ws + off);  off += (size_t)HH * H3 * sizeof(f16);
  f16* hA = (f16*)(ws + off);   off += (size_t)NR * HH * sizeof(f16);   // 8.4 MB
  f16* hB = (f16*)(ws + off);   off += (size_t)NR * HH * sizeof(f16);
  f16* hin = (f16*)(ws + off);  off += (size_t)NR * HH * sizeof(f16);
  int* fr = (int*)(ws + off);   off += NR * sizeof(int);
  int* list = (int*)(ws + off); off += NR * sizeof(int);
  int* cnt = (int*)(ws + off);  off += 64 * sizeof(int);
  (void)ws_size; (void)in_sizes; (void)n_in; (void)out_size;

  hipMemsetAsync(cnt, 0, 64 * sizeof(int), stream);
  k_prep<<<dim3(3072), 256, 0, stream>>>(Wi, Wh, resets, WiT, WhT, fr, cnt);
  k_sort<<<dim3(1), 1, 0, stream>>>(cnt);
  k_scatter<<<dim3(32), 256, 0, stream>>>(fr, cnt, list);
  k_gemm_gi<<<dim3(TBR / 64, H3 / 64), 256, 0, stream>>>(x, WiT, bi, gi);
  k_step0<<<dim3(NR * 64 / 256), 256, 0, stream>>>(resets, gi, bhn, out, hA);
  // phase 1: s=1..7; ping-pong: s odd reads hA writes hB, s even reads hB
  for (int s = 1; s < CL; ++s) {
    const f16* hrd = (s & 1) ? hA : hB;
    f16* hwr = (s & 1) ? hB : hA;
    k_phase1<<<dim3(NC, 8), 256, 0, stream>>>(s, resets, WhT, gi, bhn, out, hrd, hwr);
  }
  // chunk-end h = buffer written at s=7 (odd) = hB
  k_bound<<<dim3(NR * 64 / 256), 256, 0, stream>>>(fr, hB, h0, hin);
  k_chain<<<dim3(NR), 1024, 0, stream>>>(fr, hB, WhT, gi, bhn, h0, hin);
  for (int s = 0; s < CL; ++s)
    k_phase3<<<dim3(NR / 16), 256, 0, stream>>>(s, cnt, list, WhT, gi, bhn, out, hin);
}

// Round 5
// 1848.126 us; speedup vs baseline: 1.5475x; 1.1064x over previous
//
#include <hip/hip_runtime.h>

// ScannedRNN (flax GRUCell with per-step carry reset), T=512, B=128, H=512.
// R6b: identical to R6 (bench infra failed twice; no kernel verdict).
// k_gemm_gi rewritten as "x once, Wi from L2". One block per 64-row
// x-slice; x staged once to LDS (f16, fragment-linear order -> conflict-free
// A reads); j-loop over all 1536 cols inside the block; B fragments read
// directly from global WiT (1.5MB, L2-resident across all 1024 blocks);
// mfma_32x32x16 (2x MACs per LDS byte vs 16x16x32); no barriers in main loop.
// HBM: 1.57GB over-fetch -> ~150MB (x read once).
// Rest unchanged from R5 (sealed-chunk cut, throughput k_chain, phase3).

typedef _Float16 f16;
typedef _Float16 f16x8 __attribute__((ext_vector_type(8)));
typedef float f32x4 __attribute__((ext_vector_type(4)));
typedef float f32x16 __attribute__((ext_vector_type(16)));

#define TT 512
#define BB 128
#define HH 512
#define H3 1536
#define TBR 65536                     // TT*BB rows
#define NC 64                         // chunks
#define CL 8                          // chunk length
#define NR 8192                       // NC*BB rows of chunk-state
static const size_t PL = (size_t)TBR * HH;  // gi plane stride (elements)

__device__ __forceinline__ float sigf(float x) { return 1.f / (1.f + __expf(-x)); }

// ---------------------------------------------------------------- k_prep ----
// Weight transposes to [n][k] f16 + per-(c,b) first-reset fr + bucket counts.
__global__ __launch_bounds__(256) void k_prep(
    const float* __restrict__ Wi, const float* __restrict__ Wh,
    const int* __restrict__ resets,
    f16* __restrict__ WiT, f16* __restrict__ WhT,
    int* __restrict__ fr, int* __restrict__ cnt) {
  int idx = blockIdx.x * 256 + threadIdx.x;
  if (idx < HH * H3) {
    int n = idx >> 9;         // output col 0..1535
    int k = idx & (HH - 1);   // 0..511
    WiT[idx] = (f16)Wi[(size_t)k * H3 + n];
    WhT[idx] = (f16)Wh[(size_t)k * H3 + n];
  }
  if (idx < NR) {
    int c = idx >> 7, b = idx & 127;
    int f = CL;
    for (int s = CL - 1; s >= 0; --s)
      if (resets[(c * CL + s) * BB + b]) f = s;
    fr[idx] = f;
    atomicAdd(&cnt[f], 1);    // cnt[0..8] bucket counts (pre-zeroed)
  }
}

// ---------------------------------------------------------------- k_sort ----
// st[f] = #rows with fr > f (descending-fr bucket starts). cnt layout:
// [0..8]=bc, [16..24]=st (st[s]=cnt_gt[s] for phase3), [32..40]=wk (scatter).
__global__ void k_sort(int* __restrict__ cnt) {
  int st = 0;
  cnt[16 + 8] = 0;
  for (int f = 7; f >= 0; --f) {
    st += cnt[f + 1];
    cnt[16 + f] = st;
  }
  for (int f = 1; f <= 8; ++f) cnt[32 + f] = cnt[16 + f];
}

__global__ __launch_bounds__(256) void k_scatter(
    const int* __restrict__ fr, int* __restrict__ cnt, int* __restrict__ list) {
  int idx = blockIdx.x * 256 + threadIdx.x;
  if (idx < NR) {
    int f = fr[idx];
    if (f >= 1) {
      int pos = atomicAdd(&cnt[32 + f], 1);
      list[pos] = idx;
    }
  }
}

// ------------------------------------------------------------- k_gemm_gi ----
// gi[plane p][i][jj] = sum_k x[i,k]*Wi[k, p*512+jj] + bi.
// Block = 64 rows of x (staged once, fragment-linear f16 in LDS), j-loop
// over 6 tiles of 256 cols; 4 waves each own 64m x 64n via 32x32x16 MFMA.
// B fragments stream directly from WiT (global/L2); no barriers after stage.
__global__ __launch_bounds__(256) void k_gemm_gi(
    const float* __restrict__ x, const f16* __restrict__ WiT,
    const float* __restrict__ bi, f16* __restrict__ gi) {
  __shared__ __align__(16) f16 xs[64 * 512];   // 64 KB, fragment-linear
  const int tid = threadIdx.x;
  const int lane = tid & 63;
  const int w = tid >> 6;                      // 0..3
  const size_t i0 = (size_t)blockIdx.x * 64;

  // Stage x tile (64 rows x 512 k) as f16 MFMA-A fragments:
  // element (m,k) -> xs[(kb*2 + m>>5)*512 + ((m&31) + ((k>>3)&1)*32)*8 + (k&7)]
  // where kb = k>>4. A-frag read is then xs[(kb*2+mi)*512 + lane*8]: stride-1.
  {
    const int row = tid >> 2;                  // 0..63
    const int mi = row >> 5;
    const int lin = (row & 31) + ((tid & 1) << 5);  // (k>>3)&1 == tid&1
    const int koct = (tid & 3) * 8;
#pragma unroll 4
    for (int kb32 = 0; kb32 < 16; ++kb32) {
      const int k = kb32 * 32 + koct;
      const float* xp = x + (i0 + row) * HH + k;
      float4 v0 = *(const float4*)xp;
      float4 v1 = *(const float4*)(xp + 4);
      f16x8 a8;
      a8[0] = (f16)v0.x; a8[1] = (f16)v0.y; a8[2] = (f16)v0.z; a8[3] = (f16)v0.w;
      a8[4] = (f16)v1.x; a8[5] = (f16)v1.y; a8[6] = (f16)v1.z; a8[7] = (f16)v1.w;
      *(f16x8*)&xs[((k >> 4) * 2 + mi) * 512 + lin * 8] = a8;
    }
  }
  __syncthreads();

  const int ln31 = lane & 31;
  const int kh8 = (lane >> 5) * 8;             // k-octet within 16-chunk
  const int r4 = (lane >> 5) * 4;              // C-row offset

  for (int jt = 0; jt < 6; ++jt) {
    const int j0 = jt * 256 + w * 64;
    f32x16 acc[2][2] = {};
    const f16* bp0 = WiT + (size_t)(j0 + ln31) * HH + kh8;
    const f16* bp1 = bp0 + (size_t)32 * HH;
#pragma unroll 4
    for (int kb = 0; kb < 32; ++kb) {
      f16x8 af0 = *(const f16x8*)&xs[(kb * 2 + 0) * 512 + lane * 8];
      f16x8 af1 = *(const f16x8*)&xs[(kb * 2 + 1) * 512 + lane * 8];
      f16x8 bf0 = *(const f16x8*)(bp0 + kb * 16);
      f16x8 bf1 = *(const f16x8*)(bp1 + kb * 16);
      acc[0][0] = __builtin_amdgcn_mfma_f32_32x32x16_f16(af0, bf0, acc[0][0], 0, 0, 0);
      acc[0][1] = __builtin_amdgcn_mfma_f32_32x32x16_f16(af0, bf1, acc[0][1], 0, 0, 0);
      acc[1][0] = __builtin_amdgcn_mfma_f32_32x32x16_f16(af1, bf0, acc[1][0], 0, 0, 0);
      acc[1][1] = __builtin_amdgcn_mfma_f32_32x32x16_f16(af1, bf1, acc[1][1], 0, 0, 0);
    }
#pragma unroll
    for (int ni = 0; ni < 2; ++ni) {
      const int j = j0 + ni * 32 + ln31;       // 0..1535
      const float bj = bi[j];
      const int p = j >> 9, jj = j & 511;
#pragma unroll
      for (int mi = 0; mi < 2; ++mi)
#pragma unroll
        for (int r = 0; r < 16; ++r) {
          const int row = mi * 32 + (r & 3) + 8 * (r >> 2) + r4;
          gi[(size_t)p * PL + (i0 + row) * HH + jj] =
              (f16)(acc[mi][ni][r] + bj);
        }
    }
  }
}

// ---------------------------------------------------------------- k_step0 ----
// Macro-step s=0: h_prev = 0 for all chunk-start rows -> elementwise gates.
// Writes out[t=c*8] (garbage for prefix rows, fixed by phase 3) and hA
// (zeroed where reset at s=1).
__global__ __launch_bounds__(256) void k_step0(
    const int* __restrict__ resets, const f16* __restrict__ gi,
    const float* __restrict__ bhn, float* __restrict__ out,
    f16* __restrict__ hA) {
  int gid = blockIdx.x * 256 + threadIdx.x;     // NR*64 units of 8
  int row = gid >> 6;                           // 0..8191 (c*128+b)
  int c8 = (gid & 63) * 8;
  int c = row >> 7, b = row & 127;
  size_t girow = (size_t)c * 1024 + b;          // t=c*8 -> t*128+b
  const f16x8 g0 = *(const f16x8*)(gi + girow * HH + c8);
  const f16x8 g1 = *(const f16x8*)(gi + PL + girow * HH + c8);
  const f16x8 g2 = *(const f16x8*)(gi + 2 * PL + girow * HH + c8);
  const int z1 = resets[(c * CL + 1) * BB + b];
  float4 o[2];
  f16x8 hn;
#pragma unroll
  for (int u = 0; u < 8; ++u) {
    float r = sigf((float)g0[u]);
    float z = sigf((float)g1[u]);
    float n = tanhf((float)g2[u] + r * bhn[c8 + u]);
    float h = (1.f - z) * n;
    ((float*)o)[u] = h;
    hn[u] = z1 ? (f16)0.f : (f16)h;
  }
  *(float4*)(out + girow * HH + c8) = o[0];
  *(float4*)(out + girow * HH + c8 + 4) = o[1];
  *(f16x8*)(hA + (size_t)row * HH + c8) = hn;
}

// --------------------------------------------------------------- k_phase1 ----
// Macro-step s (1..7): [8192x512] @ WhT[512x1536] (3 gates) + fused gates.
// Grid (64 chunks, 8 j-tiles of 64). Reads h from hrd, writes hwr (ping-pong
// to avoid same-launch RAW across j-tile blocks of the same chunk).
__global__ __launch_bounds__(256, 2) void k_phase1(
    int s, const int* __restrict__ resets, const f16* __restrict__ WhT,
    const f16* __restrict__ gi, const float* __restrict__ bhn,
    float* __restrict__ out, const f16* __restrict__ hrd,
    f16* __restrict__ hwr) {
  __shared__ __align__(16) f16 As[128 * 40];   // pad 40 halfs -> 2-way banks
  __shared__ __align__(16) f16 Bs[192 * 40];
  const int tid = threadIdx.x;
  const int lane = tid & 63;
  const int w = tid >> 6;
  const int c = blockIdx.x;
  const int j0 = blockIdx.y * 64;
  const int t = c * CL + s;
  const int wm = (w & 1) * 64;
  const int wn = (w >> 1) * 32;
  const int fr = lane & 15;
  const int q8 = (lane >> 4) * 8;

  f32x4 acc[3][4][2] = {};

  for (int kb = 0; kb < 16; ++kb) {
    const int k0 = kb * 32;
#pragma unroll
    for (int uu = 0; uu < 2; ++uu) {      // A: 128 rows x 4 octets
      int u = tid + uu * 256;
      int row = u >> 2, oc = (u & 3) * 8;
      *(f16x8*)&As[row * 40 + oc] =
          *(const f16x8*)(hrd + ((size_t)(c * BB + row)) * HH + k0 + oc);
    }
#pragma unroll
    for (int uu = 0; uu < 3; ++uu) {      // B: 192 rows (3 gates x 64 cols)
      int u = tid + uu * 256;
      int row = u >> 2, oc = (u & 3) * 8;
      int g = row >> 6, j = j0 + (row & 63);
      *(f16x8*)&Bs[row * 40 + oc] =
          *(const f16x8*)(WhT + ((size_t)(g * HH + j)) * HH + k0 + oc);
    }
    __syncthreads();
    f16x8 af[4];
#pragma unroll
    for (int mi = 0; mi < 4; ++mi)
      af[mi] = *(const f16x8*)&As[(wm + mi * 16 + fr) * 40 + q8];
    f16x8 bf[3][2];
#pragma unroll
    for (int g = 0; g < 3; ++g)
#pragma unroll
      for (int ni = 0; ni < 2; ++ni)
        bf[g][ni] = *(const f16x8*)&Bs[(g * 64 + wn + ni * 16 + fr) * 40 + q8];
#pragma unroll
    for (int g = 0; g < 3; ++g)
#pragma unroll
      for (int mi = 0; mi < 4; ++mi)
#pragma unroll
        for (int ni = 0; ni < 2; ++ni)
          acc[g][mi][ni] = __builtin_amdgcn_mfma_f32_16x16x32_f16(
              af[mi], bf[g][ni], acc[g][mi][ni], 0, 0, 0);
    __syncthreads();
  }

  const int trow = (lane >> 4) * 4;
#pragma unroll
  for (int mi = 0; mi < 4; ++mi)
#pragma unroll
    for (int ni = 0; ni < 2; ++ni) {
      const int j = j0 + wn + ni * 16 + fr;
      const float bh = bhn[j];
#pragma unroll
      for (int r = 0; r < 4; ++r) {
        const int b = wm + mi * 16 + trow + r;     // 0..127
        const size_t girow = (size_t)c * 1024 + (size_t)s * BB + b;
        const float gr = (float)gi[girow * HH + j];
        const float gz = (float)gi[PL + girow * HH + j];
        const float gn = (float)gi[2 * PL + girow * HH + j];
        const float hp = (float)hrd[((size_t)(c * BB + b)) * HH + j];
        const float rr = sigf(gr + acc[0][mi][ni][r]);
        const float zz = sigf(gz + acc[1][mi][ni][r]);
        const float nn = tanhf(gn + rr * (acc[2][mi][ni][r] + bh));
        const float hnew = (1.f - zz) * nn + zz * hp;
        out[girow * HH + j] = hnew;
        int zr = (s < 7) ? resets[(t + 1) * BB + b] : 0;
        hwr[((size_t)(c * BB + b)) * HH + j] = zr ? (f16)0.f : (f16)hnew;
      }
    }
}

// ---------------------------------------------------------------- k_bound ----
// Parallel chunk-boundary fill: hin[c] = (f16)h0 (c==0) or hend[c-1] when
// chunk c-1 is sealed (contains a reset -> its exit state is exact).
// Rows whose predecessor is transparent are left for k_chain.
__global__ __launch_bounds__(256) void k_bound(
    const int* __restrict__ fr, const f16* __restrict__ hend,
    const float* __restrict__ h0, f16* __restrict__ hin) {
  int gid = blockIdx.x * 256 + threadIdx.x;     // NR*64 units of 8
  int row = gid >> 6;                           // c*128+b
  int o8 = (gid & 63) * 8;
  int c = row >> 7, b = row & 127;
  if (c == 0) {
    const float* hp = h0 + (size_t)b * HH + o8;
    float4 v0 = *(const float4*)hp;
    float4 v1 = *(const float4*)(hp + 4);
    f16x8 h;
    h[0] = (f16)v0.x; h[1] = (f16)v0.y; h[2] = (f16)v0.z; h[3] = (f16)v0.w;
    h[4] = (f16)v1.x; h[5] = (f16)v1.y; h[6] = (f16)v1.z; h[7] = (f16)v1.w;
    *(f16x8*)(hin + (size_t)row * HH + o8) = h;
  } else if (fr[row - BB] < CL) {
    *(f16x8*)(hin + (size_t)row * HH + o8) =
        *(const f16x8*)(hend + (size_t)(row - BB) * HH + o8);
  }
}

// ---------------------------------------------------------------- k_chain ----
// Transparent-run propagation, throughput-shaped. One block per candidate
// (c,b); survives only at run starts (~32 of 8192). 1024 threads = 16 waves
// (4/SIMD TLP). Per GRU step:
//   - prefetch this step's gi gate values into registers (hides HBM latency
//     under the weight stream);
//   - wave w computes rows [w*96, (w+1)*96): lane l loads WhT[n][l*8..+8]
//     (coalesced 1KB/instr, unroll-8 keeps 8 loads in flight), 8 cvt+FMA,
//     3 shfl_xor rounds reduce 64->8 lanes, dump 8 partials to LDS
//     part[8][1536] (transposed -> conflict-free pass-2);
//   - pass 2: gh[n] = sum of 8 partials; then 512-thread gate update.
// Writes hin[c+1]; continues while successor also transparent. Does NOT
// write `out` — phase 3 covers all positions of fr==8 rows.
__global__ __launch_bounds__(1024) void k_chain(
    const int* __restrict__ fr, const f16* __restrict__ hend,
    const f16* __restrict__ WhT, const f16* __restrict__ gi,
    const float* __restrict__ bhn, const float* __restrict__ h0,
    f16* __restrict__ hin) {
  const int row0 = blockIdx.x;                  // c0*128+b
  const int c0 = row0 >> 7, b = row0 & 127;
  if (fr[row0] != CL) return;                   // not transparent
  if (c0 > 0 && fr[row0 - BB] == CL) return;    // mid-run, handled by starter
  if (c0 == NC - 1) return;                     // no successor needs h_exit

  __shared__ float hs[HH];                      // 2 KB
  __shared__ float gh[H3];                      // 6 KB
  __shared__ float part[8 * H3];                // 48 KB, [u][n] transposed
  const int tid = threadIdx.x;
  const int lane = tid & 63;
  const int w = tid >> 6;                       // 0..15
  if (c0 == 0) {
    for (int i = tid; i < HH; i += 1024) hs[i] = h0[(size_t)b * HH + i];
  } else {
    for (int i = tid; i < HH; i += 1024)
      hs[i] = (float)hend[(size_t)(row0 - BB) * HH + i];
  }
  __syncthreads();

  int c = c0;
  while (c < NC - 1) {
    for (int s = 0; s < CL; ++s) {
      const size_t girow = (size_t)(c * CL + s) * BB + b;
      // prefetch gate inputs for this step (independent of matvec)
      float gr_v = 0.f, gz_v = 0.f, gn_v = 0.f, hp_v = 0.f, bh_v = 0.f;
      if (tid < HH) {
        gr_v = (float)gi[girow * HH + tid];
        gz_v = (float)gi[PL + girow * HH + tid];
        gn_v = (float)gi[2 * PL + girow * HH + tid];
        bh_v = bhn[tid];
        hp_v = hs[tid];
      }
      // lane's h fragment (same mapping for every wave)
      float hv[8];
      {
        float4 h0v = *(const float4*)&hs[lane * 8];
        float4 h1v = *(const float4*)&hs[lane * 8 + 4];
        hv[0] = h0v.x; hv[1] = h0v.y; hv[2] = h0v.z; hv[3] = h0v.w;
        hv[4] = h1v.x; hv[5] = h1v.y; hv[6] = h1v.z; hv[7] = h1v.w;
      }
      // gh[n] = sum_k WhT[n][k]*hs[k]; wave w owns rows [w*96, (w+1)*96)
      const f16* wp = WhT + (size_t)(w * 96) * HH + lane * 8;
#pragma unroll 8
      for (int r = 0; r < 96; ++r) {
        f16x8 wv = *(const f16x8*)(wp + (size_t)r * HH);
        float a = 0.f;
#pragma unroll
        for (int u = 0; u < 8; ++u) a += (float)wv[u] * hv[u];
        a += __shfl_xor(a, 32, 64);
        a += __shfl_xor(a, 16, 64);
        a += __shfl_xor(a, 8, 64);
        if (lane < 8) part[lane * H3 + (w * 96 + r)] = a;
      }
      __syncthreads();
      for (int n = tid; n < H3; n += 1024) {
        float a = part[n];
#pragma unroll
        for (int u = 1; u < 8; ++u) a += part[u * H3 + n];
        gh[n] = a;
      }
      __syncthreads();
      if (tid < HH) {
        const int j = tid;
        const float rr = sigf(gr_v + gh[j]);
        const float zz = sigf(gz_v + gh[HH + j]);
        const float nn = tanhf(gn_v + rr * (gh[2 * HH + j] + bh_v));
        hs[j] = (1.f - zz) * nn + zz * hp_v;
      }
      __syncthreads();
    }
    const int nrow = (c + 1) * BB + b;
    for (int i = tid; i < HH; i += 1024)
      hin[(size_t)nrow * HH + i] = (f16)hs[i];
    if (fr[nrow] != CL) break;   // successor sealed: chain cut
    ++c;                         // successor transparent: keep propagating
  }
}

// --------------------------------------------------------------- k_phase3 ----
// Prefix fixup, launch per s: rows with fr > s (first cnt_gt[s] of fr-sorted
// list). 16 gathered rows per block; full 3-gate GEMM vs WhT from L2.
__global__ __launch_bounds__(256) void k_phase3(
    int s, const int* __restrict__ cnt, const int* __restrict__ list,
    const f16* __restrict__ WhT, const f16* __restrict__ gi,
    const float* __restrict__ bhn, float* __restrict__ out,
    f16* __restrict__ hph) {
  const int count = cnt[16 + s];
  const int r0 = blockIdx.x * 16;
  if (r0 >= count) return;
  __shared__ __align__(16) f16 As[16 * 520];
  __shared__ int rows[16];
  const int tid = threadIdx.x;
  const int lane = tid & 63;
  const int w = tid >> 6;
  if (tid < 16) rows[tid] = (r0 + tid < count) ? list[r0 + tid] : -1;
  __syncthreads();
#pragma unroll
  for (int uu = 0; uu < 4; ++uu) {
    int u = tid + uu * 256;
    int row = u >> 6, oc = (u & 63) * 8;
    int rid = rows[row];
    f16x8 v = {};
    if (rid >= 0) v = *(const f16x8*)(hph + (size_t)rid * HH + oc);
    *(f16x8*)&As[row * 520 + oc] = v;
  }
  __syncthreads();
  const int fr16 = lane & 15;
  const int q8 = (lane >> 4) * 8;
  const int trow = (lane >> 4) * 4;
  for (int jt = 0; jt < 8; ++jt) {
    const int jb = w * 128 + jt * 16;
    f32x4 a0 = {}, a1 = {}, a2 = {};
#pragma unroll 4
    for (int kb = 0; kb < 16; ++kb) {
      const int k0 = kb * 32;
      f16x8 af = *(const f16x8*)&As[fr16 * 520 + k0 + q8];
      f16x8 b0 = *(const f16x8*)(WhT + ((size_t)(jb + fr16)) * HH + k0 + q8);
      f16x8 b1 = *(const f16x8*)(WhT + ((size_t)(HH + jb + fr16)) * HH + k0 + q8);
      f16x8 b2 = *(const f16x8*)(WhT + ((size_t)(2 * HH + jb + fr16)) * HH + k0 + q8);
      a0 = __builtin_amdgcn_mfma_f32_16x16x32_f16(af, b0, a0, 0, 0, 0);
      a1 = __builtin_amdgcn_mfma_f32_16x16x32_f16(af, b1, a1, 0, 0, 0);
      a2 = __builtin_amdgcn_mfma_f32_16x16x32_f16(af, b2, a2, 0, 0, 0);
    }
    const int j = jb + fr16;
    const float bh = bhn[j];
#pragma unroll
    for (int r = 0; r < 4; ++r) {
      const int rid = rows[trow + r];
      if (rid < 0) continue;
      const int c = rid >> 7, b = rid & 127;
      const size_t girow = (size_t)(c * CL + s) * BB + b;
      const float gr = (float)gi[girow * HH + j];
      const float gz = (float)gi[PL + girow * HH + j];
      const float gn = (float)gi[2 * PL + girow * HH + j];
      const float hp = (float)hph[(size_t)rid * HH + j];
      const float rr = sigf(gr + a0[r]);
      const float zz = sigf(gz + a1[r]);
      const float nn = tanhf(gn + rr * (a2[r] + bh));
      const float hnew = (1.f - zz) * nn + zz * hp;
      out[girow * HH + j] = hnew;
      hph[(size_t)rid * HH + j] = (f16)hnew;
    }
  }
}

// ---------------------------------------------------------------------------
extern "C" void kernel_launch(void* const* d_in, const int* in_sizes, int n_in,
                              void* d_out, int out_size, void* d_ws, size_t ws_size,
                              hipStream_t stream) {
  const float* x = (const float*)d_in[0];
  const int* resets = (const int*)d_in[1];
  const float* Wi = (const float*)d_in[2];
  const float* bi = (const float*)d_in[3];
  const float* Wh = (const float*)d_in[4];
  const float* bhn = (const float*)d_in[5];
  const float* h0 = (const float*)d_in[6];
  float* out = (float*)d_out;

  char* ws = (char*)d_ws;
  size_t off = 0;
  f16* gi = (f16*)(ws + off);   off += 3 * PL * sizeof(f16);            // 201.3 MB
  f16* WiT = (f16*)(ws + off);  off += (size_t)HH * H3 * sizeof(f16);
  f16* WhT = (f16*)(ws + off);  off += (size_t)HH * H3 * sizeof(f16);
  f16* hA = (f16*)(ws + off);   off += (size_t)NR * HH * sizeof(f16);   // 8.4 MB
  f16* hB = (f16*)(ws + off);   off += (size_t)NR * HH * sizeof(f16);
  f16* hin = (f16*)(ws + off);  off += (size_t)NR * HH * sizeof(f16);
  int* fr = (int*)(ws + off);   off += NR * sizeof(int);
  int* list = (int*)(ws + off); off += NR * sizeof(int);
  int* cnt = (int*)(ws + off);  off += 64 * sizeof(int);
  (void)ws_size; (void)in_sizes; (void)n_in; (void)out_size;

  hipMemsetAsync(cnt, 0, 64 * sizeof(int), stream);
  k_prep<<<dim3(3072), 256, 0, stream>>>(Wi, Wh, resets, WiT, WhT, fr, cnt);
  k_sort<<<dim3(1), 1, 0, stream>>>(cnt);
  k_scatter<<<dim3(32), 256, 0, stream>>>(fr, cnt, list);
  k_gemm_gi<<<dim3(TBR / 64), 256, 0, stream>>>(x, WiT, bi, gi);
  k_step0<<<dim3(NR * 64 / 256), 256, 0, stream>>>(resets, gi, bhn, out, hA);
  // phase 1: s=1..7; ping-pong: s odd reads hA writes hB, s even reads hB
  for (int s = 1; s < CL; ++s) {
    const f16* hrd = (s & 1) ? hA : hB;
    f16* hwr = (s & 1) ? hB : hA;
    k_phase1<<<dim3(NC, 8), 256, 0, stream>>>(s, resets, WhT, gi, bhn, out, hrd, hwr);
  }
  // chunk-end h = buffer written at s=7 (odd) = hB
  k_bound<<<dim3(NR * 64 / 256), 256, 0, stream>>>(fr, hB, h0, hin);
  k_chain<<<dim3(NR), 1024, 0, stream>>>(fr, hB, WhT, gi, bhn, h0, hin);
  for (int s = 0; s < CL; ++s)
    k_phase3<<<dim3(NR / 16), 256, 0, stream>>>(s, cnt, list, WhT, gi, bhn, out, hin);
}

// Round 6
// 1812.899 us; speedup vs baseline: 1.5776x; 1.0194x over previous
//
#include <hip/hip_runtime.h>

// ScannedRNN (flax GRUCell with per-step carry reset), T=512, B=128, H=512.
// R7: batched-MFMA chain. All ~32 transparent-run chains share WhT, so one
// block steps them all together: per GRU step a [32x512]@[512x1536] GEMM
// (mfma_32x32x16, batch = one M-tile; 16 waves x 3 n-tiles). h batch lives
// in LDS in MFMA-A fragment-linear order (conflict-free ds_read_b128 1KB);
// WhT is repacked once (k_prepB) into B-fragment order so weight loads are
// coalesced 1KB/instr -> per-step cost = the irreducible 1.57MB L2 stream
// (~12us) instead of R5's per-row shfl chains (~52us/step).
// Run-start list built in k_scatter; batching >32 and multi-chunk runs
// handled in-block. Rest unchanged from R6b.

typedef _Float16 f16;
typedef _Float16 f16x8 __attribute__((ext_vector_type(8)));
typedef float f32x4 __attribute__((ext_vector_type(4)));
typedef float f32x16 __attribute__((ext_vector_type(16)));

#define TT 512
#define BB 128
#define HH 512
#define H3 1536
#define TBR 65536                     // TT*BB rows
#define NC 64                         // chunks
#define CL 8                          // chunk length
#define NR 8192                       // NC*BB rows of chunk-state
static const size_t PL = (size_t)TBR * HH;  // gi plane stride (elements)

__device__ __forceinline__ float sigf(float x) { return 1.f / (1.f + __expf(-x)); }

// ---------------------------------------------------------------- k_prep ----
// Weight transposes to [n][k] f16 + per-(c,b) first-reset fr + bucket counts.
__global__ __launch_bounds__(256) void k_prep(
    const float* __restrict__ Wi, const float* __restrict__ Wh,
    const int* __restrict__ resets,
    f16* __restrict__ WiT, f16* __restrict__ WhT,
    int* __restrict__ fr, int* __restrict__ cnt) {
  int idx = blockIdx.x * 256 + threadIdx.x;
  if (idx < HH * H3) {
    int n = idx >> 9;         // output col 0..1535
    int k = idx & (HH - 1);   // 0..511
    WiT[idx] = (f16)Wi[(size_t)k * H3 + n];
    WhT[idx] = (f16)Wh[(size_t)k * H3 + n];
  }
  if (idx < NR) {
    int c = idx >> 7, b = idx & 127;
    int f = CL;
    for (int s = CL - 1; s >= 0; --s)
      if (resets[(c * CL + s) * BB + b]) f = s;
    fr[idx] = f;
    atomicAdd(&cnt[f], 1);    // cnt[0..8] bucket counts (pre-zeroed)
  }
}

// ---------------------------------------------------------------- k_prepB ----
// Repack WhT [n][k] into MFMA-B fragment-linear order for 32x32x16:
// WhTf[((t*32+kb)*64 + l)*8 + o] = WhT[(t*32 + (l&31))*512 + kb*16 + (l>>5)*8 + o]
// so a wave's B-frag load at (t,kb) is one contiguous 1KB read.
__global__ __launch_bounds__(256) void k_prepB(
    const f16* __restrict__ WhT, f16* __restrict__ WhTf) {
  int u = blockIdx.x * 256 + threadIdx.x;      // 48*32*64 = 98304 units
  int l = u & 63;
  int kb = (u >> 6) & 31;
  int t = u >> 11;
  f16x8 v = *(const f16x8*)(WhT + (size_t)(t * 32 + (l & 31)) * HH +
                            kb * 16 + (l >> 5) * 8);
  *(f16x8*)(WhTf + (size_t)u * 8) = v;
}

// ---------------------------------------------------------------- k_sort ----
// st[f] = #rows with fr > f (descending-fr bucket starts). cnt layout:
// [0..8]=bc, [16..24]=st (st[s]=cnt_gt[s] for phase3), [32..40]=wk (scatter),
// [48]=run-start count.
__global__ void k_sort(int* __restrict__ cnt) {
  int st = 0;
  cnt[16 + 8] = 0;
  for (int f = 7; f >= 0; --f) {
    st += cnt[f + 1];
    cnt[16 + f] = st;
  }
  for (int f = 1; f <= 8; ++f) cnt[32 + f] = cnt[16 + f];
}

__global__ __launch_bounds__(256) void k_scatter(
    const int* __restrict__ fr, int* __restrict__ cnt, int* __restrict__ list,
    int* __restrict__ slist) {
  int idx = blockIdx.x * 256 + threadIdx.x;
  if (idx < NR) {
    int f = fr[idx];
    if (f >= 1) {
      int pos = atomicAdd(&cnt[32 + f], 1);
      list[pos] = idx;
    }
    // transparent-run starts (chain seeds): fr==8, has successor, pred sealed
    int c = idx >> 7;
    if (f == CL && c < NC - 1 && (c == 0 || fr[idx - BB] < CL)) {
      int p = atomicAdd(&cnt[48], 1);
      slist[p] = idx;
    }
  }
}

// ------------------------------------------------------------- k_gemm_gi ----
// gi[plane p][i][jj] = sum_k x[i,k]*Wi[k, p*512+jj] + bi.
// Block = 64 rows of x (staged once, fragment-linear f16 in LDS), j-loop
// over 6 tiles of 256 cols; 4 waves each own 64m x 64n via 32x32x16 MFMA.
// B fragments stream directly from WiT (global/L2); no barriers after stage.
__global__ __launch_bounds__(256) void k_gemm_gi(
    const float* __restrict__ x, const f16* __restrict__ WiT,
    const float* __restrict__ bi, f16* __restrict__ gi) {
  __shared__ __align__(16) f16 xs[64 * 512];   // 64 KB, fragment-linear
  const int tid = threadIdx.x;
  const int lane = tid & 63;
  const int w = tid >> 6;                      // 0..3
  const size_t i0 = (size_t)blockIdx.x * 64;

  {
    const int row = tid >> 2;                  // 0..63
    const int mi = row >> 5;
    const int lin = (row & 31) + ((tid & 1) << 5);
    const int koct = (tid & 3) * 8;
#pragma unroll 4
    for (int kb32 = 0; kb32 < 16; ++kb32) {
      const int k = kb32 * 32 + koct;
      const float* xp = x + (i0 + row) * HH + k;
      float4 v0 = *(const float4*)xp;
      float4 v1 = *(const float4*)(xp + 4);
      f16x8 a8;
      a8[0] = (f16)v0.x; a8[1] = (f16)v0.y; a8[2] = (f16)v0.z; a8[3] = (f16)v0.w;
      a8[4] = (f16)v1.x; a8[5] = (f16)v1.y; a8[6] = (f16)v1.z; a8[7] = (f16)v1.w;
      *(f16x8*)&xs[((k >> 4) * 2 + mi) * 512 + lin * 8] = a8;
    }
  }
  __syncthreads();

  const int ln31 = lane & 31;
  const int kh8 = (lane >> 5) * 8;             // k-octet within 16-chunk
  const int r4 = (lane >> 5) * 4;              // C-row offset

  for (int jt = 0; jt < 6; ++jt) {
    const int j0 = jt * 256 + w * 64;
    f32x16 acc[2][2] = {};
    const f16* bp0 = WiT + (size_t)(j0 + ln31) * HH + kh8;
    const f16* bp1 = bp0 + (size_t)32 * HH;
#pragma unroll 4
    for (int kb = 0; kb < 32; ++kb) {
      f16x8 af0 = *(const f16x8*)&xs[(kb * 2 + 0) * 512 + lane * 8];
      f16x8 af1 = *(const f16x8*)&xs[(kb * 2 + 1) * 512 + lane * 8];
      f16x8 bf0 = *(const f16x8*)(bp0 + kb * 16);
      f16x8 bf1 = *(const f16x8*)(bp1 + kb * 16);
      acc[0][0] = __builtin_amdgcn_mfma_f32_32x32x16_f16(af0, bf0, acc[0][0], 0, 0, 0);
      acc[0][1] = __builtin_amdgcn_mfma_f32_32x32x16_f16(af0, bf1, acc[0][1], 0, 0, 0);
      acc[1][0] = __builtin_amdgcn_mfma_f32_32x32x16_f16(af1, bf0, acc[1][0], 0, 0, 0);
      acc[1][1] = __builtin_amdgcn_mfma_f32_32x32x16_f16(af1, bf1, acc[1][1], 0, 0, 0);
    }
#pragma unroll
    for (int ni = 0; ni < 2; ++ni) {
      const int j = j0 + ni * 32 + ln31;       // 0..1535
      const float bj = bi[j];
      const int p = j >> 9, jj = j & 511;
#pragma unroll
      for (int mi = 0; mi < 2; ++mi)
#pragma unroll
        for (int r = 0; r < 16; ++r) {
          const int row = mi * 32 + (r & 3) + 8 * (r >> 2) + r4;
          gi[(size_t)p * PL + (i0 + row) * HH + jj] =
              (f16)(acc[mi][ni][r] + bj);
        }
    }
  }
}

// ---------------------------------------------------------------- k_step0 ----
// Macro-step s=0: h_prev = 0 for all chunk-start rows -> elementwise gates.
// Writes out[t=c*8] (garbage for prefix rows, fixed by phase 3) and hA
// (zeroed where reset at s=1).
__global__ __launch_bounds__(256) void k_step0(
    const int* __restrict__ resets, const f16* __restrict__ gi,
    const float* __restrict__ bhn, float* __restrict__ out,
    f16* __restrict__ hA) {
  int gid = blockIdx.x * 256 + threadIdx.x;     // NR*64 units of 8
  int row = gid >> 6;                           // 0..8191 (c*128+b)
  int c8 = (gid & 63) * 8;
  int c = row >> 7, b = row & 127;
  size_t girow = (size_t)c * 1024 + b;          // t=c*8 -> t*128+b
  const f16x8 g0 = *(const f16x8*)(gi + girow * HH + c8);
  const f16x8 g1 = *(const f16x8*)(gi + PL + girow * HH + c8);
  const f16x8 g2 = *(const f16x8*)(gi + 2 * PL + girow * HH + c8);
  const int z1 = resets[(c * CL + 1) * BB + b];
  float4 o[2];
  f16x8 hn;
#pragma unroll
  for (int u = 0; u < 8; ++u) {
    float r = sigf((float)g0[u]);
    float z = sigf((float)g1[u]);
    float n = tanhf((float)g2[u] + r * bhn[c8 + u]);
    float h = (1.f - z) * n;
    ((float*)o)[u] = h;
    hn[u] = z1 ? (f16)0.f : (f16)h;
  }
  *(float4*)(out + girow * HH + c8) = o[0];
  *(float4*)(out + girow * HH + c8 + 4) = o[1];
  *(f16x8*)(hA + (size_t)row * HH + c8) = hn;
}

// --------------------------------------------------------------- k_phase1 ----
// Macro-step s (1..7): [8192x512] @ WhT[512x1536] (3 gates) + fused gates.
// Grid (64 chunks, 8 j-tiles of 64). Reads h from hrd, writes hwr (ping-pong
// to avoid same-launch RAW across j-tile blocks of the same chunk).
__global__ __launch_bounds__(256, 2) void k_phase1(
    int s, const int* __restrict__ resets, const f16* __restrict__ WhT,
    const f16* __restrict__ gi, const float* __restrict__ bhn,
    float* __restrict__ out, const f16* __restrict__ hrd,
    f16* __restrict__ hwr) {
  __shared__ __align__(16) f16 As[128 * 40];   // pad 40 halfs -> 2-way banks
  __shared__ __align__(16) f16 Bs[192 * 40];
  const int tid = threadIdx.x;
  const int lane = tid & 63;
  const int w = tid >> 6;
  const int c = blockIdx.x;
  const int j0 = blockIdx.y * 64;
  const int t = c * CL + s;
  const int wm = (w & 1) * 64;
  const int wn = (w >> 1) * 32;
  const int fr = lane & 15;
  const int q8 = (lane >> 4) * 8;

  f32x4 acc[3][4][2] = {};

  for (int kb = 0; kb < 16; ++kb) {
    const int k0 = kb * 32;
#pragma unroll
    for (int uu = 0; uu < 2; ++uu) {      // A: 128 rows x 4 octets
      int u = tid + uu * 256;
      int row = u >> 2, oc = (u & 3) * 8;
      *(f16x8*)&As[row * 40 + oc] =
          *(const f16x8*)(hrd + ((size_t)(c * BB + row)) * HH + k0 + oc);
    }
#pragma unroll
    for (int uu = 0; uu < 3; ++uu) {      // B: 192 rows (3 gates x 64 cols)
      int u = tid + uu * 256;
      int row = u >> 2, oc = (u & 3) * 8;
      int g = row >> 6, j = j0 + (row & 63);
      *(f16x8*)&Bs[row * 40 + oc] =
          *(const f16x8*)(WhT + ((size_t)(g * HH + j)) * HH + k0 + oc);
    }
    __syncthreads();
    f16x8 af[4];
#pragma unroll
    for (int mi = 0; mi < 4; ++mi)
      af[mi] = *(const f16x8*)&As[(wm + mi * 16 + fr) * 40 + q8];
    f16x8 bf[3][2];
#pragma unroll
    for (int g = 0; g < 3; ++g)
#pragma unroll
      for (int ni = 0; ni < 2; ++ni)
        bf[g][ni] = *(const f16x8*)&Bs[(g * 64 + wn + ni * 16 + fr) * 40 + q8];
#pragma unroll
    for (int g = 0; g < 3; ++g)
#pragma unroll
      for (int mi = 0; mi < 4; ++mi)
#pragma unroll
        for (int ni = 0; ni < 2; ++ni)
          acc[g][mi][ni] = __builtin_amdgcn_mfma_f32_16x16x32_f16(
              af[mi], bf[g][ni], acc[g][mi][ni], 0, 0, 0);
    __syncthreads();
  }

  const int trow = (lane >> 4) * 4;
#pragma unroll
  for (int mi = 0; mi < 4; ++mi)
#pragma unroll
    for (int ni = 0; ni < 2; ++ni) {
      const int j = j0 + wn + ni * 16 + fr;
      const float bh = bhn[j];
#pragma unroll
      for (int r = 0; r < 4; ++r) {
        const int b = wm + mi * 16 + trow + r;     // 0..127
        const size_t girow = (size_t)c * 1024 + (size_t)s * BB + b;
        const float gr = (float)gi[girow * HH + j];
        const float gz = (float)gi[PL + girow * HH + j];
        const float gn = (float)gi[2 * PL + girow * HH + j];
        const float hp = (float)hrd[((size_t)(c * BB + b)) * HH + j];
        const float rr = sigf(gr + acc[0][mi][ni][r]);
        const float zz = sigf(gz + acc[1][mi][ni][r]);
        const float nn = tanhf(gn + rr * (acc[2][mi][ni][r] + bh));
        const float hnew = (1.f - zz) * nn + zz * hp;
        out[girow * HH + j] = hnew;
        int zr = (s < 7) ? resets[(t + 1) * BB + b] : 0;
        hwr[((size_t)(c * BB + b)) * HH + j] = zr ? (f16)0.f : (f16)hnew;
      }
    }
}

// ---------------------------------------------------------------- k_bound ----
// Parallel chunk-boundary fill: hin[c] = (f16)h0 (c==0) or hend[c-1] when
// chunk c-1 is sealed (contains a reset -> its exit state is exact).
// Rows whose predecessor is transparent are left for k_chain2.
__global__ __launch_bounds__(256) void k_bound(
    const int* __restrict__ fr, const f16* __restrict__ hend,
    const float* __restrict__ h0, f16* __restrict__ hin) {
  int gid = blockIdx.x * 256 + threadIdx.x;     // NR*64 units of 8
  int row = gid >> 6;                           // c*128+b
  int o8 = (gid & 63) * 8;
  int c = row >> 7, b = row & 127;
  if (c == 0) {
    const float* hp = h0 + (size_t)b * HH + o8;
    float4 v0 = *(const float4*)hp;
    float4 v1 = *(const float4*)(hp + 4);
    f16x8 h;
    h[0] = (f16)v0.x; h[1] = (f16)v0.y; h[2] = (f16)v0.z; h[3] = (f16)v0.w;
    h[4] = (f16)v1.x; h[5] = (f16)v1.y; h[6] = (f16)v1.z; h[7] = (f16)v1.w;
    *(f16x8*)(hin + (size_t)row * HH + o8) = h;
  } else if (fr[row - BB] < CL) {
    *(f16x8*)(hin + (size_t)row * HH + o8) =
        *(const f16x8*)(hend + (size_t)(row - BB) * HH + o8);
  }
}

// ---------------------------------------------------------------- k_chain2 ----
// Batched transparent-run propagation. One block steps up to 32 chains
// simultaneously; per GRU step: [32x512]@[512x1536] via mfma_32x32x16.
// h batch in LDS, fragment-linear: addr(m,k) = (k>>4)*512 +
// ((m&31) + ((k>>3)&1)*32)*8 + (k&7)  => A-frag read = hsA[kb*512 + lane*8]
// (contiguous 1KB/wave instr). B from WhTf (fragment-packed, coalesced).
// Wave w owns j in [w*32, w*32+32) across all 3 gates (n-tiles w, 16+w, 32+w);
// gate update is register math off the C-layout (col=lane&31,
// row=(r&3)+8*(r>>2)+4*(lane>>5)). Chains advance to successor chunks while
// transparent; inactive slots compute garbage that is never written out.
__global__ __launch_bounds__(1024) void k_chain2(
    const int* __restrict__ fr, const f16* __restrict__ hend,
    const f16* __restrict__ WhTf, const f16* __restrict__ gi,
    const float* __restrict__ bhn, const float* __restrict__ h0,
    f16* __restrict__ hin, const int* __restrict__ slist,
    const int* __restrict__ cnt) {
  const int count = cnt[48];
  const int nbat = (count + 31) >> 5;
  __shared__ __align__(16) f16 hsA[32 * 512];   // 32 KB fragment-linear
  __shared__ int ch[32];
  __shared__ int anyact;
  const int tid = threadIdx.x;
  const int lane = tid & 63;
  const int w = tid >> 6;                       // 0..15
  const int nc = lane & 31;
  const int hi = lane >> 5;

  for (int bat = blockIdx.x; bat < nbat; bat += gridDim.x) {
    if (tid < 32) {
      int r = bat * 32 + tid;
      ch[tid] = (r < count) ? slist[r] : -1;
    }
    __syncthreads();
    // init h rows (fragment-linear store)
    for (int u = tid; u < 32 * 64; u += 1024) {
      int m = u >> 6, o8 = (u & 63) * 8;
      int cr = ch[m];
      f16x8 h = {};
      if (cr >= 0) {
        if ((cr >> 7) == 0) {
          const float* hp = h0 + (size_t)(cr & 127) * HH + o8;
          float4 v0 = *(const float4*)hp;
          float4 v1 = *(const float4*)(hp + 4);
          h[0] = (f16)v0.x; h[1] = (f16)v0.y; h[2] = (f16)v0.z; h[3] = (f16)v0.w;
          h[4] = (f16)v1.x; h[5] = (f16)v1.y; h[6] = (f16)v1.z; h[7] = (f16)v1.w;
        } else {
          h = *(const f16x8*)(hend + (size_t)(cr - BB) * HH + o8);
        }
      }
      *(f16x8*)&hsA[(o8 >> 4) * 512 + (m + ((o8 >> 3) & 1) * 32) * 8] = h;
    }
    __syncthreads();

    while (true) {
      for (int s = 0; s < CL; ++s) {
        // ---- MFMA phase: wave w computes n-tiles {w, 16+w, 32+w} ----
        f32x16 a0 = {}, a1 = {}, a2 = {};
        const f16* b0p = WhTf + ((size_t)(w)*32 * 64 + lane) * 8;
        const f16* b1p = WhTf + ((size_t)(16 + w) * 32 * 64 + lane) * 8;
        const f16* b2p = WhTf + ((size_t)(32 + w) * 32 * 64 + lane) * 8;
#pragma unroll 4
        for (int kb = 0; kb < 32; ++kb) {
          f16x8 af = *(const f16x8*)&hsA[kb * 512 + lane * 8];
          f16x8 bf0 = *(const f16x8*)(b0p + (size_t)kb * 512);
          f16x8 bf1 = *(const f16x8*)(b1p + (size_t)kb * 512);
          f16x8 bf2 = *(const f16x8*)(b2p + (size_t)kb * 512);
          a0 = __builtin_amdgcn_mfma_f32_32x32x16_f16(af, bf0, a0, 0, 0, 0);
          a1 = __builtin_amdgcn_mfma_f32_32x32x16_f16(af, bf1, a1, 0, 0, 0);
          a2 = __builtin_amdgcn_mfma_f32_32x32x16_f16(af, bf2, a2, 0, 0, 0);
        }
        __syncthreads();
        // ---- gate update: j = w*32 + nc for all 3 gates ----
        const int j = w * 32 + nc;
        const float bh = bhn[j];
#pragma unroll
        for (int r = 0; r < 16; ++r) {
          const int m = (r & 3) + 8 * (r >> 2) + 4 * hi;
          const int cr = ch[m];
          const size_t girow =
              (cr >= 0)
                  ? ((size_t)(cr >> 7) * 1024 + (size_t)s * BB + (cr & 127))
                  : 0;
          const float gr = (float)gi[girow * HH + j];
          const float gz = (float)gi[PL + girow * HH + j];
          const float gn = (float)gi[2 * PL + girow * HH + j];
          const int ha =
              (j >> 4) * 512 + (m + ((j >> 3) & 1) * 32) * 8 + (j & 7);
          const float hp = (float)hsA[ha];
          const float rr = sigf(gr + a0[r]);
          const float zz = sigf(gz + a1[r]);
          const float nn = tanhf(gn + rr * (a2[r] + bh));
          hsA[ha] = (f16)((1.f - zz) * nn + zz * hp);
        }
        __syncthreads();
      }
      // ---- chunk end: write hin[successor], advance active chains ----
      for (int u = tid; u < 32 * 64; u += 1024) {
        int m = u >> 6, o8 = (u & 63) * 8;
        int cr = ch[m];
        if (cr >= 0) {
          f16x8 h = *(const f16x8*)&hsA[(o8 >> 4) * 512 +
                                        (m + ((o8 >> 3) & 1) * 32) * 8];
          *(f16x8*)(hin + (size_t)(cr + BB) * HH + o8) = h;
        }
      }
      if (tid == 0) anyact = 0;
      __syncthreads();
      if (tid < 32) {
        int cr = ch[tid];
        if (cr >= 0) {
          int nrow = cr + BB;
          if (fr[nrow] == CL && (nrow >> 7) < NC - 1) {
            ch[tid] = nrow;
            atomicAdd(&anyact, 1);
          } else {
            ch[tid] = -1;
          }
        }
      }
      __syncthreads();
      if (anyact == 0) break;
    }
    __syncthreads();
  }
}

// --------------------------------------------------------------- k_phase3 ----
// Prefix fixup, launch per s: rows with fr > s (first cnt_gt[s] of fr-sorted
// list). 16 gathered rows per block; full 3-gate GEMM vs WhT from L2.
__global__ __launch_bounds__(256) void k_phase3(
    int s, const int* __restrict__ cnt, const int* __restrict__ list,
    const f16* __restrict__ WhT, const f16* __restrict__ gi,
    const float* __restrict__ bhn, float* __restrict__ out,
    f16* __restrict__ hph) {
  const int count = cnt[16 + s];
  const int r0 = blockIdx.x * 16;
  if (r0 >= count) return;
  __shared__ __align__(16) f16 As[16 * 520];
  __shared__ int rows[16];
  const int tid = threadIdx.x;
  const int lane = tid & 63;
  const int w = tid >> 6;
  if (tid < 16) rows[tid] = (r0 + tid < count) ? list[r0 + tid] : -1;
  __syncthreads();
#pragma unroll
  for (int uu = 0; uu < 4; ++uu) {
    int u = tid + uu * 256;
    int row = u >> 6, oc = (u & 63) * 8;
    int rid = rows[row];
    f16x8 v = {};
    if (rid >= 0) v = *(const f16x8*)(hph + (size_t)rid * HH + oc);
    *(f16x8*)&As[row * 520 + oc] = v;
  }
  __syncthreads();
  const int fr16 = lane & 15;
  const int q8 = (lane >> 4) * 8;
  const int trow = (lane >> 4) * 4;
  for (int jt = 0; jt < 8; ++jt) {
    const int jb = w * 128 + jt * 16;
    f32x4 a0 = {}, a1 = {}, a2 = {};
#pragma unroll 4
    for (int kb = 0; kb < 16; ++kb) {
      const int k0 = kb * 32;
      f16x8 af = *(const f16x8*)&As[fr16 * 520 + k0 + q8];
      f16x8 b0 = *(const f16x8*)(WhT + ((size_t)(jb + fr16)) * HH + k0 + q8);
      f16x8 b1 = *(const f16x8*)(WhT + ((size_t)(HH + jb + fr16)) * HH + k0 + q8);
      f16x8 b2 = *(const f16x8*)(WhT + ((size_t)(2 * HH + jb + fr16)) * HH + k0 + q8);
      a0 = __builtin_amdgcn_mfma_f32_16x16x32_f16(af, b0, a0, 0, 0, 0);
      a1 = __builtin_amdgcn_mfma_f32_16x16x32_f16(af, b1, a1, 0, 0, 0);
      a2 = __builtin_amdgcn_mfma_f32_16x16x32_f16(af, b2, a2, 0, 0, 0);
    }
    const int j = jb + fr16;
    const float bh = bhn[j];
#pragma unroll
    for (int r = 0; r < 4; ++r) {
      const int rid = rows[trow + r];
      if (rid < 0) continue;
      const int c = rid >> 7, b = rid & 127;
      const size_t girow = (size_t)(c * CL + s) * BB + b;
      const float gr = (float)gi[girow * HH + j];
      const float gz = (float)gi[PL + girow * HH + j];
      const float gn = (float)gi[2 * PL + girow * HH + j];
      const float hp = (float)hph[(size_t)rid * HH + j];
      const float rr = sigf(gr + a0[r]);
      const float zz = sigf(gz + a1[r]);
      const float nn = tanhf(gn + rr * (a2[r] + bh));
      const float hnew = (1.f - zz) * nn + zz * hp;
      out[girow * HH + j] = hnew;
      hph[(size_t)rid * HH + j] = (f16)hnew;
    }
  }
}

// ---------------------------------------------------------------------------
extern "C" void kernel_launch(void* const* d_in, const int* in_sizes, int n_in,
                              void* d_out, int out_size, void* d_ws, size_t ws_size,
                              hipStream_t stream) {
  const float* x = (const float*)d_in[0];
  const int* resets = (const int*)d_in[1];
  const float* Wi = (const float*)d_in[2];
  const float* bi = (const float*)d_in[3];
  const float* Wh = (const float*)d_in[4];
  const float* bhn = (const float*)d_in[5];
  const float* h0 = (const float*)d_in[6];
  float* out = (float*)d_out;

  char* ws = (char*)d_ws;
  size_t off = 0;
  f16* gi = (f16*)(ws + off);    off += 3 * PL * sizeof(f16);            // 201.3 MB
  f16* WiT = (f16*)(ws + off);   off += (size_t)HH * H3 * sizeof(f16);
  f16* WhT = (f16*)(ws + off);   off += (size_t)HH * H3 * sizeof(f16);
  f16* WhTf = (f16*)(ws + off);  off += (size_t)HH * H3 * sizeof(f16);   // frag-packed
  f16* hA = (f16*)(ws + off);    off += (size_t)NR * HH * sizeof(f16);   // 8.4 MB
  f16* hB = (f16*)(ws + off);    off += (size_t)NR * HH * sizeof(f16);
  f16* hin = (f16*)(ws + off);   off += (size_t)NR * HH * sizeof(f16);
  int* fr = (int*)(ws + off);    off += NR * sizeof(int);
  int* list = (int*)(ws + off);  off += NR * sizeof(int);
  int* slist = (int*)(ws + off); off += NR * sizeof(int);
  int* cnt = (int*)(ws + off);   off += 64 * sizeof(int);
  (void)ws_size; (void)in_sizes; (void)n_in; (void)out_size;

  hipMemsetAsync(cnt, 0, 64 * sizeof(int), stream);
  k_prep<<<dim3(3072), 256, 0, stream>>>(Wi, Wh, resets, WiT, WhT, fr, cnt);
  k_prepB<<<dim3(384), 256, 0, stream>>>(WhT, WhTf);
  k_sort<<<dim3(1), 1, 0, stream>>>(cnt);
  k_scatter<<<dim3(32), 256, 0, stream>>>(fr, cnt, list, slist);
  k_gemm_gi<<<dim3(TBR / 64), 256, 0, stream>>>(x, WiT, bi, gi);
  k_step0<<<dim3(NR * 64 / 256), 256, 0, stream>>>(resets, gi, bhn, out, hA);
  // phase 1: s=1..7; ping-pong: s odd reads hA writes hB, s even reads hB
  for (int s = 1; s < CL; ++s) {
    const f16* hrd = (s & 1) ? hA : hB;
    f16* hwr = (s & 1) ? hB : hA;
    k_phase1<<<dim3(NC, 8), 256, 0, stream>>>(s, resets, WhT, gi, bhn, out, hrd, hwr);
  }
  // chunk-end h = buffer written at s=7 (odd) = hB
  k_bound<<<dim3(NR * 64 / 256), 256, 0, stream>>>(fr, hB, h0, hin);
  k_chain2<<<dim3(4), 1024, 0, stream>>>(fr, hB, WhTf, gi, bhn, h0, hin, slist, cnt);
  for (int s = 0; s < CL; ++s)
    k_phase3<<<dim3(NR / 16), 256, 0, stream>>>(s, cnt, list, WhT, gi, bhn, out, hin);
}

// Round 7
// 1723.005 us; speedup vs baseline: 1.6599x; 1.0522x over previous
//
#include <hip/hip_runtime.h>

// ScannedRNN (flax GRUCell with per-step carry reset), T=512, B=128, H=512.
// R8: (1) k_phase1 rewritten in the batched-MFMA style: 256 blocks x 1024
// threads, 32 h-rows staged frag-linear to LDS once, 16 waves x {3 gate
// n-tiles} with B streamed coalesced from fragment-packed WhTf, gates fused
// in registers off the 32x32 C-layout. ~145us -> ~20us per launch.
// (2) k_chain2 hsA XOR bank-swizzle slot = (m+hi*32)^hi^((kb&1)<<1): the
// gate-update scalar RMW becomes conflict-free (was 8-way, 80K conflict
// cycles = ~33us/CU); MFMA A-read uses 2 precomputed per-lane bases.
// (3) k_gemm_gi B from fragment-packed WiTf (k_prepB packs both weights).

typedef _Float16 f16;
typedef _Float16 f16x8 __attribute__((ext_vector_type(8)));
typedef float f32x4 __attribute__((ext_vector_type(4)));
typedef float f32x16 __attribute__((ext_vector_type(16)));

#define TT 512
#define BB 128
#define HH 512
#define H3 1536
#define TBR 65536                     // TT*BB rows
#define NC 64                         // chunks
#define CL 8                          // chunk length
#define NR 8192                       // NC*BB rows of chunk-state
static const size_t PL = (size_t)TBR * HH;  // gi plane stride (elements)

__device__ __forceinline__ float sigf(float x) { return 1.f / (1.f + __expf(-x)); }

// ---------------------------------------------------------------- k_prep ----
// Weight transposes to [n][k] f16 + per-(c,b) first-reset fr + bucket counts.
__global__ __launch_bounds__(256) void k_prep(
    const float* __restrict__ Wi, const float* __restrict__ Wh,
    const int* __restrict__ resets,
    f16* __restrict__ WiT, f16* __restrict__ WhT,
    int* __restrict__ fr, int* __restrict__ cnt) {
  int idx = blockIdx.x * 256 + threadIdx.x;
  if (idx < HH * H3) {
    int n = idx >> 9;         // output col 0..1535
    int k = idx & (HH - 1);   // 0..511
    WiT[idx] = (f16)Wi[(size_t)k * H3 + n];
    WhT[idx] = (f16)Wh[(size_t)k * H3 + n];
  }
  if (idx < NR) {
    int c = idx >> 7, b = idx & 127;
    int f = CL;
    for (int s = CL - 1; s >= 0; --s)
      if (resets[(c * CL + s) * BB + b]) f = s;
    fr[idx] = f;
    atomicAdd(&cnt[f], 1);    // cnt[0..8] bucket counts (pre-zeroed)
  }
}

// ---------------------------------------------------------------- k_prepB ----
// Repack W*T [n][k] into MFMA-B fragment order for 32x32x16:
// Wf[((t*32+kb)*64 + l)*8 + o] = WT[(t*32 + (l&31))*512 + kb*16 + (l>>5)*8 + o]
// so a wave's B-frag load at (t,kb) is one contiguous 1KB read.
__global__ __launch_bounds__(256) void k_prepB(
    const f16* __restrict__ WhT, const f16* __restrict__ WiT,
    f16* __restrict__ WhTf, f16* __restrict__ WiTf) {
  int idx = blockIdx.x * 256 + threadIdx.x;    // 2 * 48*32*64 = 196608 units
  const f16* src = WhT;
  f16* dst = WhTf;
  int u = idx;
  if (idx >= 98304) { src = WiT; dst = WiTf; u = idx - 98304; }
  int l = u & 63;
  int kb = (u >> 6) & 31;
  int t = u >> 11;
  f16x8 v = *(const f16x8*)(src + (size_t)(t * 32 + (l & 31)) * HH +
                            kb * 16 + (l >> 5) * 8);
  *(f16x8*)(dst + (size_t)u * 8) = v;
}

// ---------------------------------------------------------------- k_sort ----
// cnt layout: [0..8]=bc, [16..24]=st (cnt_gt[s] for phase3), [32..40]=wk,
// [48]=run-start count.
__global__ void k_sort(int* __restrict__ cnt) {
  int st = 0;
  cnt[16 + 8] = 0;
  for (int f = 7; f >= 0; --f) {
    st += cnt[f + 1];
    cnt[16 + f] = st;
  }
  for (int f = 1; f <= 8; ++f) cnt[32 + f] = cnt[16 + f];
}

__global__ __launch_bounds__(256) void k_scatter(
    const int* __restrict__ fr, int* __restrict__ cnt, int* __restrict__ list,
    int* __restrict__ slist) {
  int idx = blockIdx.x * 256 + threadIdx.x;
  if (idx < NR) {
    int f = fr[idx];
    if (f >= 1) {
      int pos = atomicAdd(&cnt[32 + f], 1);
      list[pos] = idx;
    }
    // transparent-run starts (chain seeds): fr==8, has successor, pred sealed
    int c = idx >> 7;
    if (f == CL && c < NC - 1 && (c == 0 || fr[idx - BB] < CL)) {
      int p = atomicAdd(&cnt[48], 1);
      slist[p] = idx;
    }
  }
}

// ------------------------------------------------------------- k_gemm_gi ----
// gi[plane p][i][jj] = sum_k x[i,k]*Wi[k, p*512+jj] + bi.
// Block = 64 rows of x (staged once, fragment-linear f16 in LDS), j-loop
// over 6 tiles of 256 cols; 4 waves each own 64m x 64n via 32x32x16 MFMA.
// B fragments stream coalesced from fragment-packed WiTf (L2-resident).
__global__ __launch_bounds__(256) void k_gemm_gi(
    const float* __restrict__ x, const f16* __restrict__ WiTf,
    const float* __restrict__ bi, f16* __restrict__ gi) {
  __shared__ __align__(16) f16 xs[64 * 512];   // 64 KB, fragment-linear
  const int tid = threadIdx.x;
  const int lane = tid & 63;
  const int w = tid >> 6;                      // 0..3
  const size_t i0 = (size_t)blockIdx.x * 64;

  {
    const int row = tid >> 2;                  // 0..63
    const int mi = row >> 5;
    const int lin = (row & 31) + ((tid & 1) << 5);
    const int koct = (tid & 3) * 8;
#pragma unroll 4
    for (int kb32 = 0; kb32 < 16; ++kb32) {
      const int k = kb32 * 32 + koct;
      const float* xp = x + (i0 + row) * HH + k;
      float4 v0 = *(const float4*)xp;
      float4 v1 = *(const float4*)(xp + 4);
      f16x8 a8;
      a8[0] = (f16)v0.x; a8[1] = (f16)v0.y; a8[2] = (f16)v0.z; a8[3] = (f16)v0.w;
      a8[4] = (f16)v1.x; a8[5] = (f16)v1.y; a8[6] = (f16)v1.z; a8[7] = (f16)v1.w;
      *(f16x8*)&xs[((k >> 4) * 2 + mi) * 512 + lin * 8] = a8;
    }
  }
  __syncthreads();

  const int ln31 = lane & 31;
  const int r4 = (lane >> 5) * 4;              // C-row offset

  for (int jt = 0; jt < 6; ++jt) {
    const int t0 = jt * 8 + w * 2;             // n-tile pair
    f32x16 acc[2][2] = {};
    const f16* bp0 = WiTf + ((size_t)t0 * 2048 + lane) * 8;
    const f16* bp1 = WiTf + ((size_t)(t0 + 1) * 2048 + lane) * 8;
#pragma unroll 4
    for (int kb = 0; kb < 32; ++kb) {
      f16x8 af0 = *(const f16x8*)&xs[(kb * 2 + 0) * 512 + lane * 8];
      f16x8 af1 = *(const f16x8*)&xs[(kb * 2 + 1) * 512 + lane * 8];
      f16x8 bf0 = *(const f16x8*)(bp0 + (size_t)kb * 512);
      f16x8 bf1 = *(const f16x8*)(bp1 + (size_t)kb * 512);
      acc[0][0] = __builtin_amdgcn_mfma_f32_32x32x16_f16(af0, bf0, acc[0][0], 0, 0, 0);
      acc[0][1] = __builtin_amdgcn_mfma_f32_32x32x16_f16(af0, bf1, acc[0][1], 0, 0, 0);
      acc[1][0] = __builtin_amdgcn_mfma_f32_32x32x16_f16(af1, bf0, acc[1][0], 0, 0, 0);
      acc[1][1] = __builtin_amdgcn_mfma_f32_32x32x16_f16(af1, bf1, acc[1][1], 0, 0, 0);
    }
#pragma unroll
    for (int ni = 0; ni < 2; ++ni) {
      const int j = (t0 + ni) * 32 + ln31;     // 0..1535
      const float bj = bi[j];
      const int p = j >> 9, jj = j & 511;
#pragma unroll
      for (int mi = 0; mi < 2; ++mi)
#pragma unroll
        for (int r = 0; r < 16; ++r) {
          const int row = mi * 32 + (r & 3) + 8 * (r >> 2) + r4;
          gi[(size_t)p * PL + (i0 + row) * HH + jj] =
              (f16)(acc[mi][ni][r] + bj);
        }
    }
  }
}

// ---------------------------------------------------------------- k_step0 ----
// Macro-step s=0: h_prev = 0 for all chunk-start rows -> elementwise gates.
__global__ __launch_bounds__(256) void k_step0(
    const int* __restrict__ resets, const f16* __restrict__ gi,
    const float* __restrict__ bhn, float* __restrict__ out,
    f16* __restrict__ hA) {
  int gid = blockIdx.x * 256 + threadIdx.x;     // NR*64 units of 8
  int row = gid >> 6;                           // 0..8191 (c*128+b)
  int c8 = (gid & 63) * 8;
  int c = row >> 7, b = row & 127;
  size_t girow = (size_t)c * 1024 + b;          // t=c*8 -> t*128+b
  const f16x8 g0 = *(const f16x8*)(gi + girow * HH + c8);
  const f16x8 g1 = *(const f16x8*)(gi + PL + girow * HH + c8);
  const f16x8 g2 = *(const f16x8*)(gi + 2 * PL + girow * HH + c8);
  const int z1 = resets[(c * CL + 1) * BB + b];
  float4 o[2];
  f16x8 hn;
#pragma unroll
  for (int u = 0; u < 8; ++u) {
    float r = sigf((float)g0[u]);
    float z = sigf((float)g1[u]);
    float n = tanhf((float)g2[u] + r * bhn[c8 + u]);
    float h = (1.f - z) * n;
    ((float*)o)[u] = h;
    hn[u] = z1 ? (f16)0.f : (f16)h;
  }
  *(float4*)(out + girow * HH + c8) = o[0];
  *(float4*)(out + girow * HH + c8 + 4) = o[1];
  *(f16x8*)(hA + (size_t)row * HH + c8) = hn;
}

// --------------------------------------------------------------- k_phase1 ----
// Macro-step s (1..7): [8192x512] @ Wh[512x1536] (3 gates) + fused gates.
// 256 blocks x 1024 threads; block owns 32 h-rows (one chunk quarter),
// staged once to LDS fragment-linear; wave w owns j in [w*32,w*32+32) across
// all 3 gates (WhTf n-tiles w, 16+w, 32+w), B streamed coalesced from L2.
// Gate fusion in registers off C-layout (col=lane&31, row=(r&3)+8*(r>>2)+4*hi).
__global__ __launch_bounds__(1024) void k_phase1(
    int s, const int* __restrict__ resets, const f16* __restrict__ WhTf,
    const f16* __restrict__ gi, const float* __restrict__ bhn,
    float* __restrict__ out, const f16* __restrict__ hrd,
    f16* __restrict__ hwr) {
  __shared__ __align__(16) f16 hsA[32 * 512];   // 32 KB fragment-linear
  const int tid = threadIdx.x;
  const int lane = tid & 63;
  const int w = tid >> 6;                       // 0..15
  const int gr0 = blockIdx.x * 32;              // h-row base (within chunk)
  const int c = gr0 >> 7;
  const int t = c * CL + s;

  for (int u = tid; u < 32 * 64; u += 1024) {
    int m = u >> 6, o8 = (u & 63) * 8;
    f16x8 h = *(const f16x8*)(hrd + (size_t)(gr0 + m) * HH + o8);
    *(f16x8*)&hsA[(o8 >> 4) * 512 + (m + ((o8 >> 3) & 1) * 32) * 8] = h;
  }
  __syncthreads();

  f32x16 a0 = {}, a1 = {}, a2 = {};
  const f16* b0p = WhTf + ((size_t)w * 2048 + lane) * 8;
  const f16* b1p = WhTf + ((size_t)(16 + w) * 2048 + lane) * 8;
  const f16* b2p = WhTf + ((size_t)(32 + w) * 2048 + lane) * 8;
#pragma unroll 4
  for (int kb = 0; kb < 32; ++kb) {
    f16x8 af = *(const f16x8*)&hsA[kb * 512 + lane * 8];
    f16x8 bf0 = *(const f16x8*)(b0p + (size_t)kb * 512);
    f16x8 bf1 = *(const f16x8*)(b1p + (size_t)kb * 512);
    f16x8 bf2 = *(const f16x8*)(b2p + (size_t)kb * 512);
    a0 = __builtin_amdgcn_mfma_f32_32x32x16_f16(af, bf0, a0, 0, 0, 0);
    a1 = __builtin_amdgcn_mfma_f32_32x32x16_f16(af, bf1, a1, 0, 0, 0);
    a2 = __builtin_amdgcn_mfma_f32_32x32x16_f16(af, bf2, a2, 0, 0, 0);
  }

  const int nc = lane & 31;
  const int hi = lane >> 5;
  const int j = w * 32 + nc;
  const float bh = bhn[j];
#pragma unroll
  for (int r = 0; r < 16; ++r) {
    const int m = (r & 3) + 8 * (r >> 2) + 4 * hi;
    const int gr = gr0 + m;
    const int b = gr & 127;
    const size_t girow = (size_t)c * 1024 + (size_t)s * BB + b;
    const float grv = (float)gi[girow * HH + j];
    const float gzv = (float)gi[PL + girow * HH + j];
    const float gnv = (float)gi[2 * PL + girow * HH + j];
    const float hp = (float)hrd[(size_t)gr * HH + j];
    const float rr = sigf(grv + a0[r]);
    const float zz = sigf(gzv + a1[r]);
    const float nn = tanhf(gnv + rr * (a2[r] + bh));
    const float hnew = (1.f - zz) * nn + zz * hp;
    out[girow * HH + j] = hnew;
    int zr = (s < 7) ? resets[(t + 1) * BB + b] : 0;
    hwr[(size_t)gr * HH + j] = zr ? (f16)0.f : (f16)hnew;
  }
}

// ---------------------------------------------------------------- k_bound ----
// Parallel chunk-boundary fill: hin[c] = (f16)h0 (c==0) or hend[c-1] when
// chunk c-1 is sealed. Rows with transparent predecessor left for k_chain2.
__global__ __launch_bounds__(256) void k_bound(
    const int* __restrict__ fr, const f16* __restrict__ hend,
    const float* __restrict__ h0, f16* __restrict__ hin) {
  int gid = blockIdx.x * 256 + threadIdx.x;     // NR*64 units of 8
  int row = gid >> 6;                           // c*128+b
  int o8 = (gid & 63) * 8;
  int c = row >> 7, b = row & 127;
  if (c == 0) {
    const float* hp = h0 + (size_t)b * HH + o8;
    float4 v0 = *(const float4*)hp;
    float4 v1 = *(const float4*)(hp + 4);
    f16x8 h;
    h[0] = (f16)v0.x; h[1] = (f16)v0.y; h[2] = (f16)v0.z; h[3] = (f16)v0.w;
    h[4] = (f16)v1.x; h[5] = (f16)v1.y; h[6] = (f16)v1.z; h[7] = (f16)v1.w;
    *(f16x8*)(hin + (size_t)row * HH + o8) = h;
  } else if (fr[row - BB] < CL) {
    *(f16x8*)(hin + (size_t)row * HH + o8) =
        *(const f16x8*)(hend + (size_t)(row - BB) * HH + o8);
  }
}

// ---------------------------------------------------------------- k_chain2 ----
// Batched transparent-run propagation (one block, ~32 chains, 8 steps).
// hsA layout XOR-swizzled: element (m,k) at
//   addr = (k>>4)*512 + slot*8 + (k&7),  slot = (m + hi*32) ^ hi ^ (kbp<<1),
//   hi=(k>>3)&1, kbp=(k>>4)&1.
// Gate-update scalar RMW bank = ((m%8)^hi^(2*kbp))*4 + (j&7)>>1 -> 32 banks
// x 2 lanes = conflict-free (was 8-way, ~33us/CU of conflict cycles).
// MFMA A-read uses two precomputed per-lane slot bases (even/odd kb).
__global__ __launch_bounds__(1024) void k_chain2(
    const int* __restrict__ fr, const f16* __restrict__ hend,
    const f16* __restrict__ WhTf, const f16* __restrict__ gi,
    const float* __restrict__ bhn, const float* __restrict__ h0,
    f16* __restrict__ hin, const int* __restrict__ slist,
    const int* __restrict__ cnt) {
  const int count = cnt[48];
  const int nbat = (count + 31) >> 5;
  __shared__ __align__(16) f16 hsA[32 * 512];   // 32 KB
  __shared__ int ch[32];
  __shared__ int anyact;
  const int tid = threadIdx.x;
  const int lane = tid & 63;
  const int w = tid >> 6;                       // 0..15
  const int nc = lane & 31;
  const int hi = lane >> 5;
  const int sl0 = (lane ^ (lane >> 5)) * 8;     // A-frag slot base, kb even
  const int sl1 = sl0 ^ 16;                     // kb odd (slot ^ 2, *8)

  for (int bat = blockIdx.x; bat < nbat; bat += gridDim.x) {
    if (tid < 32) {
      int r = bat * 32 + tid;
      ch[tid] = (r < count) ? slist[r] : -1;
    }
    __syncthreads();
    // init h rows (swizzled fragment store)
    for (int u = tid; u < 32 * 64; u += 1024) {
      int m = u >> 6, oct = u & 63;
      int cr = ch[m];
      f16x8 h = {};
      if (cr >= 0) {
        if ((cr >> 7) == 0) {
          const float* hp = h0 + (size_t)(cr & 127) * HH + oct * 8;
          float4 v0 = *(const float4*)hp;
          float4 v1 = *(const float4*)(hp + 4);
          h[0] = (f16)v0.x; h[1] = (f16)v0.y; h[2] = (f16)v0.z; h[3] = (f16)v0.w;
          h[4] = (f16)v1.x; h[5] = (f16)v1.y; h[6] = (f16)v1.z; h[7] = (f16)v1.w;
        } else {
          h = *(const f16x8*)(hend + (size_t)(cr - BB) * HH + oct * 8);
        }
      }
      int slot = (m + (oct & 1) * 32) ^ (oct & 1) ^ (((oct >> 1) & 1) << 1);
      *(f16x8*)&hsA[(oct >> 1) * 512 + slot * 8] = h;
    }
    __syncthreads();

    while (true) {
      for (int s = 0; s < CL; ++s) {
        f32x16 a0 = {}, a1 = {}, a2 = {};
        const f16* b0p = WhTf + ((size_t)w * 2048 + lane) * 8;
        const f16* b1p = WhTf + ((size_t)(16 + w) * 2048 + lane) * 8;
        const f16* b2p = WhTf + ((size_t)(32 + w) * 2048 + lane) * 8;
#pragma unroll 4
        for (int kb = 0; kb < 32; ++kb) {
          const int sb = (kb & 1) ? sl1 : sl0;
          f16x8 af = *(const f16x8*)&hsA[kb * 512 + sb];
          f16x8 bf0 = *(const f16x8*)(b0p + (size_t)kb * 512);
          f16x8 bf1 = *(const f16x8*)(b1p + (size_t)kb * 512);
          f16x8 bf2 = *(const f16x8*)(b2p + (size_t)kb * 512);
          a0 = __builtin_amdgcn_mfma_f32_32x32x16_f16(af, bf0, a0, 0, 0, 0);
          a1 = __builtin_amdgcn_mfma_f32_32x32x16_f16(af, bf1, a1, 0, 0, 0);
          a2 = __builtin_amdgcn_mfma_f32_32x32x16_f16(af, bf2, a2, 0, 0, 0);
        }
        __syncthreads();   // all waves done reading hsA before RMW
        const int j = w * 32 + nc;
        const float bh = bhn[j];
        const int jhi = (j >> 3) & 1;
        const int jkb = j >> 4;
        const int swz = jhi ^ ((jkb & 1) << 1);
#pragma unroll
        for (int r = 0; r < 16; ++r) {
          const int m = (r & 3) + 8 * (r >> 2) + 4 * hi;
          const int cr = ch[m];
          const size_t girow =
              (cr >= 0)
                  ? ((size_t)(cr >> 7) * 1024 + (size_t)s * BB + (cr & 127))
                  : 0;
          const float grv = (float)gi[girow * HH + j];
          const float gzv = (float)gi[PL + girow * HH + j];
          const float gnv = (float)gi[2 * PL + girow * HH + j];
          const int slot = (m + jhi * 32) ^ swz;
          const int ha = jkb * 512 + slot * 8 + (j & 7);
          const float hp = (float)hsA[ha];
          const float rr = sigf(grv + a0[r]);
          const float zz = sigf(gzv + a1[r]);
          const float nn = tanhf(gnv + rr * (a2[r] + bh));
          hsA[ha] = (f16)((1.f - zz) * nn + zz * hp);
        }
        __syncthreads();
      }
      // chunk end: write hin[successor], advance active chains
      for (int u = tid; u < 32 * 64; u += 1024) {
        int m = u >> 6, oct = u & 63;
        int cr = ch[m];
        if (cr >= 0) {
          int slot = (m + (oct & 1) * 32) ^ (oct & 1) ^ (((oct >> 1) & 1) << 1);
          f16x8 h = *(const f16x8*)&hsA[(oct >> 1) * 512 + slot * 8];
          *(f16x8*)(hin + (size_t)(cr + BB) * HH + oct * 8) = h;
        }
      }
      if (tid == 0) anyact = 0;
      __syncthreads();
      if (tid < 32) {
        int cr = ch[tid];
        if (cr >= 0) {
          int nrow = cr + BB;
          if (fr[nrow] == CL && (nrow >> 7) < NC - 1) {
            ch[tid] = nrow;
            atomicAdd(&anyact, 1);
          } else {
            ch[tid] = -1;
          }
        }
      }
      __syncthreads();
      if (anyact == 0) break;
    }
    __syncthreads();
  }
}

// --------------------------------------------------------------- k_phase3 ----
// Prefix fixup, launch per s: rows with fr > s (first cnt_gt[s] of fr-sorted
// list). 16 gathered rows per block; full 3-gate GEMM vs WhT from L2.
__global__ __launch_bounds__(256) void k_phase3(
    int s, const int* __restrict__ cnt, const int* __restrict__ list,
    const f16* __restrict__ WhT, const f16* __restrict__ gi,
    const float* __restrict__ bhn, float* __restrict__ out,
    f16* __restrict__ hph) {
  const int count = cnt[16 + s];
  const int r0 = blockIdx.x * 16;
  if (r0 >= count) return;
  __shared__ __align__(16) f16 As[16 * 520];
  __shared__ int rows[16];
  const int tid = threadIdx.x;
  const int lane = tid & 63;
  const int w = tid >> 6;
  if (tid < 16) rows[tid] = (r0 + tid < count) ? list[r0 + tid] : -1;
  __syncthreads();
#pragma unroll
  for (int uu = 0; uu < 4; ++uu) {
    int u = tid + uu * 256;
    int row = u >> 6, oc = (u & 63) * 8;
    int rid = rows[row];
    f16x8 v = {};
    if (rid >= 0) v = *(const f16x8*)(hph + (size_t)rid * HH + oc);
    *(f16x8*)&As[row * 520 + oc] = v;
  }
  __syncthreads();
  const int fr16 = lane & 15;
  const int q8 = (lane >> 4) * 8;
  const int trow = (lane >> 4) * 4;
  for (int jt = 0; jt < 8; ++jt) {
    const int jb = w * 128 + jt * 16;
    f32x4 a0 = {}, a1 = {}, a2 = {};
#pragma unroll 4
    for (int kb = 0; kb < 16; ++kb) {
      const int k0 = kb * 32;
      f16x8 af = *(const f16x8*)&As[fr16 * 520 + k0 + q8];
      f16x8 b0 = *(const f16x8*)(WhT + ((size_t)(jb + fr16)) * HH + k0 + q8);
      f16x8 b1 = *(const f16x8*)(WhT + ((size_t)(HH + jb + fr16)) * HH + k0 + q8);
      f16x8 b2 = *(const f16x8*)(WhT + ((size_t)(2 * HH + jb + fr16)) * HH + k0 + q8);
      a0 = __builtin_amdgcn_mfma_f32_16x16x32_f16(af, b0, a0, 0, 0, 0);
      a1 = __builtin_amdgcn_mfma_f32_16x16x32_f16(af, b1, a1, 0, 0, 0);
      a2 = __builtin_amdgcn_mfma_f32_16x16x32_f16(af, b2, a2, 0, 0, 0);
    }
    const int j = jb + fr16;
    const float bh = bhn[j];
#pragma unroll
    for (int r = 0; r < 4; ++r) {
      const int rid = rows[trow + r];
      if (rid < 0) continue;
      const int c = rid >> 7, b = rid & 127;
      const size_t girow = (size_t)(c * CL + s) * BB + b;
      const float gr = (float)gi[girow * HH + j];
      const float gz = (float)gi[PL + girow * HH + j];
      const float gn = (float)gi[2 * PL + girow * HH + j];
      const float hp = (float)hph[(size_t)rid * HH + j];
      const float rr = sigf(gr + a0[r]);
      const float zz = sigf(gz + a1[r]);
      const float nn = tanhf(gn + rr * (a2[r] + bh));
      const float hnew = (1.f - zz) * nn + zz * hp;
      out[girow * HH + j] = hnew;
      hph[(size_t)rid * HH + j] = (f16)hnew;
    }
  }
}

// ---------------------------------------------------------------------------
extern "C" void kernel_launch(void* const* d_in, const int* in_sizes, int n_in,
                              void* d_out, int out_size, void* d_ws, size_t ws_size,
                              hipStream_t stream) {
  const float* x = (const float*)d_in[0];
  const int* resets = (const int*)d_in[1];
  const float* Wi = (const float*)d_in[2];
  const float* bi = (const float*)d_in[3];
  const float* Wh = (const float*)d_in[4];
  const float* bhn = (const float*)d_in[5];
  const float* h0 = (const float*)d_in[6];
  float* out = (float*)d_out;

  char* ws = (char*)d_ws;
  size_t off = 0;
  f16* gi = (f16*)(ws + off);    off += 3 * PL * sizeof(f16);            // 201.3 MB
  f16* WiT = (f16*)(ws + off);   off += (size_t)HH * H3 * sizeof(f16);
  f16* WhT = (f16*)(ws + off);   off += (size_t)HH * H3 * sizeof(f16);
  f16* WhTf = (f16*)(ws + off);  off += (size_t)HH * H3 * sizeof(f16);   // frag-packed
  f16* WiTf = (f16*)(ws + off);  off += (size_t)HH * H3 * sizeof(f16);   // frag-packed
  f16* hA = (f16*)(ws + off);    off += (size_t)NR * HH * sizeof(f16);   // 8.4 MB
  f16* hB = (f16*)(ws + off);    off += (size_t)NR * HH * sizeof(f16);
  f16* hin = (f16*)(ws + off);   off += (size_t)NR * HH * sizeof(f16);
  int* fr = (int*)(ws + off);    off += NR * sizeof(int);
  int* list = (int*)(ws + off);  off += NR * sizeof(int);
  int* slist = (int*)(ws + off); off += NR * sizeof(int);
  int* cnt = (int*)(ws + off);   off += 64 * sizeof(int);
  (void)ws_size; (void)in_sizes; (void)n_in; (void)out_size;

  hipMemsetAsync(cnt, 0, 64 * sizeof(int), stream);
  k_prep<<<dim3(3072), 256, 0, stream>>>(Wi, Wh, resets, WiT, WhT, fr, cnt);
  k_prepB<<<dim3(768), 256, 0, stream>>>(WhT, WiT, WhTf, WiTf);
  k_sort<<<dim3(1), 1, 0, stream>>>(cnt);
  k_scatter<<<dim3(32), 256, 0, stream>>>(fr, cnt, list, slist);
  k_gemm_gi<<<dim3(TBR / 64), 256, 0, stream>>>(x, WiTf, bi, gi);
  k_step0<<<dim3(NR * 64 / 256), 256, 0, stream>>>(resets, gi, bhn, out, hA);
  // phase 1: s=1..7; ping-pong: s odd reads hA writes hB, s even reads hB
  for (int s = 1; s < CL; ++s) {
    const f16* hrd = (s & 1) ? hA : hB;
    f16* hwr = (s & 1) ? hB : hA;
    k_phase1<<<dim3(NR / 32), 1024, 0, stream>>>(s, resets, WhTf, gi, bhn, out,
                                                 hrd, hwr);
  }
  // chunk-end h = buffer written at s=7 (odd) = hB
  k_bound<<<dim3(NR * 64 / 256), 256, 0, stream>>>(fr, hB, h0, hin);
  k_chain2<<<dim3(4), 1024, 0, stream>>>(fr, hB, WhTf, gi, bhn, h0, hin, slist, cnt);
  for (int s = 0; s < CL; ++s)
    k_phase3<<<dim3(NR / 16), 256, 0, stream>>>(s, cnt, list, WhT, gi, bhn, out, hin);
}